// Round 14
// baseline (880.315 us; speedup 1.0000x reference)
//
#include <hip/hip_runtime.h>
#include <cstdint>

// Problem constants (match reference setup_inputs)
#define NNODE 40000
#define NEDGE 120000
#define NHE   16384
#define CCH   512
#define MPAD  40064   // 313 * 128, padded row count for GEMM A operands

typedef __attribute__((ext_vector_type(8))) short bf16x8;
typedef __attribute__((ext_vector_type(4))) float f32x4;
typedef __attribute__((ext_vector_type(8))) unsigned short ushort8;
typedef __attribute__((ext_vector_type(4))) unsigned short ushort4v;

// ---------------------------------------------------------------- helpers
__device__ __forceinline__ unsigned short f2bf(float f) {
  unsigned int u = __float_as_uint(f);
  u += 0x7FFFu + ((u >> 16) & 1u);   // round-to-nearest-even
  return (unsigned short)(u >> 16);
}
__device__ __forceinline__ float bf2f(unsigned short u) {
  return __uint_as_float((unsigned int)u << 16);
}

__device__ __forceinline__ void g2l16(const void* g, void* l) {
  // async global->LDS, 16B per lane. LDS dest must be wave-uniform base + lane*16.
  __builtin_amdgcn_global_load_lds(
      (const __attribute__((address_space(1))) unsigned int*)(uintptr_t)g,
      (__attribute__((address_space(3))) unsigned int*)(unsigned int)(uintptr_t)l,
      16, 0, 0);
}

// bijective XCD swizzle (m204): blocks with consecutive pid land on the same XCD
__device__ __forceinline__ int xcd_pid(int lin, int nwg) {
  int xcd = lin & 7, slot = lin >> 3;
  int q = nwg >> 3, r = nwg & 7;
  return ((xcd < r) ? (xcd * (q + 1)) : (r * (q + 1) + (xcd - r) * q)) + slot;
}

// ---------------------------------------------------------------- prep: x->bf16 + 6 transposes + 4 histograms
struct TPack {
  const float* W[6];
  unsigned short* Wt[6];
  int ld[6];
  int kOff[6];
};
__global__ void prep_cvt(const float* __restrict__ xa, const float* __restrict__ xb,
                         unsigned short* __restrict__ oa, unsigned short* __restrict__ ob,
                         long nValid, long nTotal, int half, TPack p,
                         const int* __restrict__ hA, const int* __restrict__ hB,
                         const int* __restrict__ nA, const int* __restrict__ nB,
                         int* __restrict__ cntHA, int* __restrict__ cntHB,
                         int* __restrict__ cntNA, int* __restrict__ cntNB, int E) {
  int bid = blockIdx.x;
  if (bid < 2 * half) {
    int t = bid >= half;
    long i = ((long)(bid - t * half) * 256 + threadIdx.x) * 8;
    if (i >= nTotal) return;
    const float* in = t ? xb : xa;
    unsigned short* out = t ? ob : oa;
    ushort8 r;
    if (i < nValid) {
      float4 a = *(const float4*)(in + i);
      float4 b = *(const float4*)(in + i + 4);
      r[0] = f2bf(a.x); r[1] = f2bf(a.y); r[2] = f2bf(a.z); r[3] = f2bf(a.w);
      r[4] = f2bf(b.x); r[5] = f2bf(b.y); r[6] = f2bf(b.z); r[7] = f2bf(b.w);
    } else {
      for (int j = 0; j < 8; ++j) r[j] = 0;
    }
    *(ushort8*)(out + i) = r;
  } else if (bid < 2 * half + 6144) {
    int wb = bid - 2 * half;                    // 0..6143
    int which = wb >> 10;                       // 1024 blocks per matrix
    int gid = (wb & 1023) * 256 + threadIdx.x;
    int i = gid >> 9, j = gid & 511;            // W[i][j]
    p.Wt[which][(size_t)j * p.ld[which] + p.kOff[which] + i] = f2bf(p.W[which][gid]);
  } else {
    int e = (bid - 2 * half - 6144) * 256 + threadIdx.x;
    if (e >= E) return;
    atomicAdd(&cntHA[hA[e]], 1);
    atomicAdd(&cntHB[hB[e]], 1);
    atomicAdd(&cntNA[nA[e]], 1);
    atomicAdd(&cntNB[nB[e]], 1);
  }
}

// aW for both types, rows scaled by inv[t*8 + head(k)] (folds softmax denominator)
__global__ void tscale2(const float* __restrict__ Wa, const float* __restrict__ Wb,
                        const float* __restrict__ inv,
                        unsigned short* __restrict__ Wta, unsigned short* __restrict__ Wtb) {
  int t = blockIdx.x >> 10;
  int gid = (blockIdx.x & 1023) * 256 + threadIdx.x;
  int i = gid >> 9, j = gid & 511;              // W[i][j], i is the k index
  const float* W = t ? Wb : Wa;
  unsigned short* Wt = t ? Wtb : Wta;
  Wt[(size_t)j * 1024 + i] = f2bf(W[gid] * inv[t * 8 + (i >> 6)]);
}

// ---------------------------------------------------------------- CSR build
// 4 independent single-block exclusive scans; zeroes cnt in place (becomes cursor)
__global__ void scan4(int* __restrict__ c0, int* __restrict__ b0, int n0,
                      int* __restrict__ c1, int* __restrict__ b1, int n1,
                      int* __restrict__ c2, int* __restrict__ b2, int n2,
                      int* __restrict__ c3, int* __restrict__ b3, int n3) {
  __shared__ int part[1024];
  int* cnt; int* base; int n;
  if (blockIdx.x == 0) { cnt = c0; base = b0; n = n0; }
  else if (blockIdx.x == 1) { cnt = c1; base = b1; n = n1; }
  else if (blockIdx.x == 2) { cnt = c2; base = b2; n = n2; }
  else { cnt = c3; base = b3; n = n3; }
  int tid = threadIdx.x;
  int chunk = (n + 1023) >> 10;
  int lo = tid * chunk;
  int hi = lo + chunk; if (hi > n) hi = n;
  int s = 0;
  for (int i = lo; i < hi; ++i) s += cnt[i];
  part[tid] = s;
  __syncthreads();
  for (int off = 1; off < 1024; off <<= 1) {
    int v = (tid >= off) ? part[tid - off] : 0;
    __syncthreads();
    part[tid] += v;
    __syncthreads();
  }
  int excl = (tid == 0) ? 0 : part[tid - 1];
  for (int i = lo; i < hi; ++i) { base[i] = excl; excl += cnt[i]; cnt[i] = 0; }
  if (tid == 0) base[n] = part[1023];
}

// fills all 4 CSR value arrays (he-CSR stores node ids; node-CSR stores he ids)
__global__ void fill4(const int* __restrict__ hA, const int* __restrict__ hB,
                      const int* __restrict__ nA, const int* __restrict__ nB,
                      const int* __restrict__ baseHA, const int* __restrict__ baseHB,
                      const int* __restrict__ baseNA, const int* __restrict__ baseNB,
                      int* __restrict__ curHA, int* __restrict__ curHB,
                      int* __restrict__ curNA, int* __restrict__ curNB,
                      int* __restrict__ nArrHA, int* __restrict__ nArrHB,
                      int* __restrict__ hArrNA, int* __restrict__ hArrNB, int E) {
  int e = blockIdx.x * 256 + threadIdx.x;
  if (e >= E) return;
  int ha = hA[e], hb = hB[e], na = nA[e], nb = nB[e];
  int p;
  p = atomicAdd(&curHA[ha], 1); nArrHA[baseHA[ha] + p] = na;
  p = atomicAdd(&curHB[hb], 1); nArrHB[baseHB[hb] + p] = nb;
  p = atomicAdd(&curNA[na], 1); hArrNA[baseNA[na] + p] = ha;
  p = atomicAdd(&curNB[nb], 1); hArrNB[baseNB[nb] + p] = hb;
}

// ---------------------------------------------------------------- Xagg gather (both types, 2-deep pipelined)
__global__ void xagg2(const unsigned short* __restrict__ Xa, const int* __restrict__ nArrA,
                      const int* __restrict__ baseA, unsigned short* __restrict__ Oa,
                      const unsigned short* __restrict__ Xb, const int* __restrict__ nArrB,
                      const int* __restrict__ baseB, unsigned short* __restrict__ Ob, int half) {
  int t = blockIdx.x >= half;
  int bl = blockIdx.x - t * half;
  const unsigned short* X = t ? Xb : Xa;
  const int* nArr = t ? nArrB : nArrA;
  const int* base = t ? baseB : baseA;
  unsigned short* Xagg = t ? Ob : Oa;
  int h = bl * 2 + (threadIdx.x >> 7);
  if (h >= NHE) return;
  int sub = threadIdx.x & 127;
  int c4 = sub << 2;
  float ax = 0.f, ay = 0.f, az = 0.f, aw = 0.f;
  int b0 = base[h], b1 = base[h + 1];
  int n0 = (b0 < b1) ? nArr[b0] : 0;
  int n1 = (b0 + 1 < b1) ? nArr[b0 + 1] : 0;
  ushort4v vA = *(const ushort4v*)&X[(size_t)n0 * CCH + c4];
  ushort4v vB = *(const ushort4v*)&X[(size_t)n1 * CCH + c4];
  for (int i = b0; i < b1; ++i) {
    ushort4v v = vA;
    vA = vB;
    int n2 = (i + 2 < b1) ? nArr[i + 2] : 0;
    vB = *(const ushort4v*)&X[(size_t)n2 * CCH + c4];   // 2-deep prefetch
    ax += bf2f(v[0]); ay += bf2f(v[1]); az += bf2f(v[2]); aw += bf2f(v[3]);
  }
  ushort4v r = {f2bf(ax), f2bf(ay), f2bf(az), f2bf(aw)};
  *(ushort4v*)&Xagg[(size_t)h * CCH + c4] = r;
}

// ---------------------------------------------------------------- fused attention (both types, 2-deep pipelined)
__global__ void fused_attn2(const unsigned short* __restrict__ Qa,
                            const unsigned short* __restrict__ Qbb,
                            const unsigned short* __restrict__ heb,
                            const int* __restrict__ hArrA, const int* __restrict__ baseA,
                            const int* __restrict__ hArrB, const int* __restrict__ baseB,
                            unsigned short* __restrict__ nbfA, unsigned short* __restrict__ nbfB,
                            float* __restrict__ partials, int half) {
  __shared__ float lsum[8];
  if (threadIdx.x < 8) lsum[threadIdx.x] = 0.f;
  __syncthreads();
  int t = blockIdx.x >= half;
  int bl = blockIdx.x - t * half;
  const unsigned short* Qb = t ? Qbb : Qa;
  const int* hArr = t ? hArrB : hArrA;
  const int* base = t ? baseB : baseA;
  unsigned short* nbf = t ? nbfB : nbfA;
  int node = bl * 4 + (threadIdx.x >> 6);           // covers MPAD exactly
  int lane = threadIdx.x & 63;
  int d0 = lane << 3;                               // 8 channels per lane, head = lane>>3
  float acc[8] = {0.f, 0.f, 0.f, 0.f, 0.f, 0.f, 0.f, 0.f};
  float psum = 0.f;
  if (node < NNODE) {
    ushort8 qv = *(const ushort8*)&Qb[(size_t)node * CCH + d0];
    float q[8];
#pragma unroll
    for (int j = 0; j < 8; ++j) q[j] = bf2f(qv[j]);
    int i0 = base[node], i1 = base[node + 1];
    int h0 = (i0 < i1) ? hArr[i0] : 0;
    int h1 = (i0 + 1 < i1) ? hArr[i0 + 1] : 0;
    ushort8 kvA = *(const ushort8*)&heb[(size_t)h0 * CCH + d0];
    ushort8 kvB = *(const ushort8*)&heb[(size_t)h1 * CCH + d0];
    for (int i = i0; i < i1; ++i) {
      ushort8 kv = kvA;
      kvA = kvB;
      int h2 = (i + 2 < i1) ? hArr[i + 2] : 0;
      kvB = *(const ushort8*)&heb[(size_t)h2 * CCH + d0];   // 2-deep prefetch
      float k[8];
#pragma unroll
      for (int j = 0; j < 8; ++j) k[j] = bf2f(kv[j]);
      float d = q[0] * k[0] + q[1] * k[1] + q[2] * k[2] + q[3] * k[3] +
                q[4] * k[4] + q[5] * k[5] + q[6] * k[6] + q[7] * k[7];
      d += __shfl_xor(d, 1); d += __shfl_xor(d, 2); d += __shfl_xor(d, 4);
      float a = __expf(d * 0.125f);   // scale = 1/sqrt(64); logits bounded, no max pass
      psum += a;
#pragma unroll
      for (int j = 0; j < 8; ++j) acc[j] += a * k[j];
    }
  }
  ushort8 r;
#pragma unroll
  for (int j = 0; j < 8; ++j) r[j] = f2bf(acc[j]);
  *(ushort8*)&nbf[(size_t)node * CCH + d0] = r;     // pad rows get zeros
  if ((lane & 7) == 0) atomicAdd(&lsum[lane >> 3], psum);
  __syncthreads();
  if (threadIdx.x < 8) partials[(size_t)blockIdx.x * 8 + threadIdx.x] = lsum[threadIdx.x];
}

// partials[2*half][8] -> inv[16]; one block per (type,head)
__global__ void reduce_partials2(const float* __restrict__ partials, float* __restrict__ inv,
                                 int half) {
  __shared__ float ls[256];
  int hh = blockIdx.x;                    // 0..15
  int t = hh >> 3, h = hh & 7;
  float s = 0.f;
  for (int i = threadIdx.x; i < half; i += 256) s += partials[(size_t)(t * half + i) * 8 + h];
  ls[threadIdx.x] = s;
  __syncthreads();
  for (int off = 128; off > 0; off >>= 1) {
    if (threadIdx.x < off) ls[threadIdx.x] += ls[threadIdx.x + off];
    __syncthreads();
  }
  if (threadIdx.x == 0) inv[hh] = 1.0f / ls[0];
}

// ---------------------------------------------------------------- GEMM body (bf16 MFMA)
// 128x128 tile, BK=32, 2-phase double-buffered LDS (stage(next) || compute(cur)),
// one barrier per K-step. LDS = exactly 32 KB (staging 32 KB; C-tile reuses it
// at stride 128 with an XOR chunk swizzle) -> 5 blocks/CU (was 4 at 33 KB).
// C-tile swizzle: key = ((lrow>>2)&3) ^ (lrow&3); col' = col ^ (key<<3).
// Keys are distinct across the write-side row set (delta 4) AND the read-side
// row set (delta 1) -> both phases <= 2-way bank aliasing (free).
// bf16 output via LDS-staged epilogue (coalesced ushort8 writes).
template <int KDIM, bool ROWCNT>
__device__ __forceinline__ void gemm_body(
    unsigned short* SH, int pid,
    const unsigned short* __restrict__ A0, const unsigned short* __restrict__ A1,
    const unsigned short* __restrict__ Bt, const float* __restrict__ bias,
    const float* __restrict__ bias2, const int* __restrict__ cntA,
    const int* __restrict__ cntB, unsigned short* __restrict__ outb, int M) {
  unsigned short* As = SH;
  unsigned short* Bs = SH + 8192;
  const int row0 = (pid >> 2) * 128;
  const int col0 = (pid & 3) * 128;
  const int tid = threadIdx.x;
  const int lane = tid & 63;
  const int w = tid >> 6;
  const int wr = w >> 1, wc = w & 1;            // 2x2 waves -> 64x64 per wave

  auto stage = [&](int buf, int kt) {
#pragma unroll
    for (int j = 0; j < 2; ++j) {
      int c = tid + j * 256;                    // 16B chunk: row = c>>2, k8 = (c&3)*8
      int r = c >> 2, k8 = (c & 3) << 3;
      const unsigned short* asrc;
      if (KDIM == 512 || kt < 512)
        asrc = A0 + (size_t)(row0 + r) * 512 + kt + k8;
      else
        asrc = A1 + (size_t)(row0 + r) * 512 + (kt - 512) + k8;
      g2l16(asrc, &As[buf * 4096 + c * 8]);
      g2l16(Bt + (size_t)(col0 + r) * KDIM + kt + k8, &Bs[buf * 4096 + c * 8]);
    }
  };

  f32x4 acc[4][4];
#pragma unroll
  for (int m = 0; m < 4; ++m)
#pragma unroll
    for (int n = 0; n < 4; ++n) acc[m][n] = f32x4{0.f, 0.f, 0.f, 0.f};

  constexpr int NSTEP = KDIM / 32;
  stage(0, 0);
  __syncthreads();                              // buf0 ready
  int buf = 0;
  const int r16 = lane & 15, kh = (lane >> 4) << 3;
  for (int s = 0; s < NSTEP; ++s) {
    if (s + 1 < NSTEP) stage(buf ^ 1, (s + 1) * 32);   // prefetch next K-tile
    bf16x8 a[4], b[4];
#pragma unroll
    for (int m = 0; m < 4; ++m)
      a[m] = *(const bf16x8*)&As[buf * 4096 + (wr * 64 + m * 16 + r16) * 32 + kh];
#pragma unroll
    for (int n = 0; n < 4; ++n)
      b[n] = *(const bf16x8*)&Bs[buf * 4096 + (wc * 64 + n * 16 + r16) * 32 + kh];
#pragma unroll
    for (int m = 0; m < 4; ++m)
#pragma unroll
      for (int n = 0; n < 4; ++n)
        acc[m][n] = __builtin_amdgcn_mfma_f32_16x16x32_bf16(a[m], b[n], acc[m][n], 0, 0, 0);
    __syncthreads();                            // drains vmcnt: next buf ready, this buf free
    buf ^= 1;
  }

  // ---- epilogue: bias (+cnt terms) -> LDS C tile (XOR chunk swizzle) -> coalesced writes
  const int c15 = lane & 15;
  const int cgrp = (lane >> 4) * 4;
  float bvv[4], bv2v[4];
#pragma unroll
  for (int n = 0; n < 4; ++n) {
    int col = col0 + wc * 64 + n * 16 + c15;
    bvv[n] = bias[col];
    if (ROWCNT) bv2v[n] = bias2[col];
    else if (bias2) bvv[n] += bias2[col];
  }
#pragma unroll
  for (int m = 0; m < 4; ++m) {
#pragma unroll
    for (int r2 = 0; r2 < 4; ++r2) {
      int lrow = wr * 64 + m * 16 + cgrp + r2;
      int key = ((lrow >> 2) & 3) ^ (lrow & 3);
      float ca = 0.f, cb = 0.f;
      if (ROWCNT) {
        int row = row0 + lrow;
        ca = (float)(cntA[row + 1] - cntA[row]);
        cb = (float)(cntB[row + 1] - cntB[row]);
      }
#pragma unroll
      for (int n = 0; n < 4; ++n) {
        float v = acc[m][n][r2];
        if (ROWCNT) v += ca * bvv[n] + cb * bv2v[n];
        else v += bvv[n];
        int colL = wc * 64 + n * 16 + c15;
        SH[lrow * 128 + (colL ^ (key << 3))] = f2bf(v);
      }
    }
  }
  __syncthreads();
#pragma unroll
  for (int j = 0; j < 8; ++j) {
    int idx = tid + j * 256;                    // 2048 ushort8 chunks
    int lrow = idx >> 4, cch = idx & 15;
    int key = ((lrow >> 2) & 3) ^ (lrow & 3);
    int grow = row0 + lrow;
    if (grow < M)
      *(ushort8*)&outb[(size_t)grow * 512 + col0 + (cch << 3)] =
          *(const ushort8*)&SH[lrow * 128 + ((cch ^ key) << 3)];
  }
}

// he GEMM: he = [XaggA|XaggB] @ [kWa;kWb] + cntA*kbA + cntB*kbB  (bf16 out)
__global__ __launch_bounds__(256, 5) void gemm_he(
    const unsigned short* __restrict__ A0, const unsigned short* __restrict__ A1,
    const unsigned short* __restrict__ Bt, const float* __restrict__ kbA,
    const float* __restrict__ kbB, const int* __restrict__ cntA,
    const int* __restrict__ cntB, unsigned short* __restrict__ outb) {
  __shared__ unsigned short SH[128 * 128];
  int pid = xcd_pid(blockIdx.x, gridDim.x);
  gemm_body<1024, true>(SH, pid, A0, A1, Bt, kbA, kbB, cntA, cntB, outb, NHE);
}

// dual Q GEMM (both types in one launch, bf16 out)
__global__ __launch_bounds__(256, 5) void gemm_q2(
    int G1,
    const unsigned short* __restrict__ Aa, const unsigned short* __restrict__ Bta,
    const float* __restrict__ biasa, unsigned short* __restrict__ outa,
    const unsigned short* __restrict__ Ab, const unsigned short* __restrict__ Btb,
    const float* __restrict__ biasb, unsigned short* __restrict__ outbB) {
  __shared__ unsigned short SH[128 * 128];
  int pid = xcd_pid(blockIdx.x, gridDim.x);
  if (pid < G1)
    gemm_body<512, false>(SH, pid, Aa, Aa, Bta, biasa, nullptr, nullptr, nullptr,
                          outa, NNODE);
  else
    gemm_body<512, false>(SH, pid - G1, Ab, Ab, Btb, biasb, nullptr, nullptr, nullptr,
                          outbB, NNODE);
}

// dual combined GEMM: cbf = bf16( nbf @ (inv*aW) + ab + x @ sW + sb )   (K=1024)
__global__ __launch_bounds__(256, 5) void gemm_c2(
    int G1,
    const unsigned short* __restrict__ A0a, const unsigned short* __restrict__ A1a,
    const unsigned short* __restrict__ Bta, const float* __restrict__ aba,
    const float* __restrict__ sba, unsigned short* __restrict__ outa,
    const unsigned short* __restrict__ A0b, const unsigned short* __restrict__ A1b,
    const unsigned short* __restrict__ Btb, const float* __restrict__ abb,
    const float* __restrict__ sbb, unsigned short* __restrict__ outb) {
  __shared__ unsigned short SH[128 * 128];
  int pid = xcd_pid(blockIdx.x, gridDim.x);
  if (pid < G1)
    gemm_body<1024, false>(SH, pid, A0a, A1a, Bta, aba, sba, nullptr, nullptr,
                           outa, NNODE);
  else
    gemm_body<1024, false>(SH, pid - G1, A0b, A1b, Btb, abb, sbb, nullptr, nullptr,
                           outb, NNODE);
}

// ---------------------------------------------------------------- LayerNorm (bf16 in, f32 out, both types)
__global__ void ln2bf(const unsigned short* __restrict__ cbf, float* __restrict__ y,
                      const float* __restrict__ ga, const float* __restrict__ ba,
                      const float* __restrict__ gb, const float* __restrict__ bb) {
  int row = blockIdx.x * 4 + (threadIdx.x >> 6);
  if (row >= 2 * NNODE) return;
  int t = row >= NNODE;
  const float* g = t ? gb : ga;
  const float* b = t ? bb : ba;
  int lane = threadIdx.x & 63;
  int d0 = lane * 8;
  const unsigned short* yr = cbf + (size_t)(t ? MPAD : 0) * CCH +
                             (size_t)(row - t * NNODE) * CCH;
  ushort8 v8 = *(const ushort8*)(yr + d0);
  float vv[8];
#pragma unroll
  for (int j = 0; j < 8; ++j) vv[j] = bf2f(v8[j]);
  float s = 0.f;
#pragma unroll
  for (int j = 0; j < 8; ++j) s += vv[j];
#pragma unroll
  for (int off = 1; off < 64; off <<= 1) s += __shfl_xor(s, off);
  float mu = s * (1.0f / 512.0f);
  float sq = 0.f;
#pragma unroll
  for (int j = 0; j < 8; ++j) { float d = vv[j] - mu; sq += d * d; }
#pragma unroll
  for (int off = 1; off < 64; off <<= 1) sq += __shfl_xor(sq, off);
  float rs = rsqrtf(sq * (1.0f / 512.0f) + 1e-5f);
  float4 g0 = *(const float4*)(g + d0), g1 = *(const float4*)(g + d0 + 4);
  float4 b0 = *(const float4*)(b + d0), b1 = *(const float4*)(b + d0 + 4);
  float gg[8] = {g0.x, g0.y, g0.z, g0.w, g1.x, g1.y, g1.z, g1.w};
  float bbv[8] = {b0.x, b0.y, b0.z, b0.w, b1.x, b1.y, b1.z, b1.w};
  float o[8];
#pragma unroll
  for (int j = 0; j < 8; ++j) o[j] = gg[j] * (vv[j] - mu) * rs + bbv[j];
  float* outr = y + (size_t)row * CCH;
  *(float4*)(outr + d0) = float4{o[0], o[1], o[2], o[3]};
  *(float4*)(outr + d0 + 4) = float4{o[4], o[5], o[6], o[7]};
}

// ---------------------------------------------------------------- host
extern "C" void kernel_launch(void* const* d_in, const int* in_sizes, int n_in,
                              void* d_out, int out_size, void* d_ws, size_t ws_size,
                              hipStream_t stream) {
  const float* x_a = (const float*)d_in[0];
  const float* x_b = (const float*)d_in[1];
  const int* nidx[2] = {(const int*)d_in[2], (const int*)d_in[4]};
  const int* hidx[2] = {(const int*)d_in[3], (const int*)d_in[5]};
  const float *kW[2], *kb[2], *qW[2], *qb[2], *aW[2], *ab[2], *sW[2], *sb[2], *lng[2], *lnb[2];
  for (int t = 0; t < 2; ++t) {
    int base = 7 + t * 10;
    kW[t] = (const float*)d_in[base + 0]; kb[t] = (const float*)d_in[base + 1];
    qW[t] = (const float*)d_in[base + 2]; qb[t] = (const float*)d_in[base + 3];
    aW[t] = (const float*)d_in[base + 4]; ab[t] = (const float*)d_in[base + 5];
    sW[t] = (const float*)d_in[base + 6]; sb[t] = (const float*)d_in[base + 7];
    lng[t] = (const float*)d_in[base + 8]; lnb[t] = (const float*)d_in[base + 9];
  }

  // ---------------- workspace layout
  const size_t SZ_XBF = (size_t)MPAD * CCH * 2;         // 41 MB
  const size_t SZ_HEB = (size_t)NHE * CCH * 2;          // 16.8 MB
  const int NBLK_ATTN = MPAD / 4;                       // 10016 per type
  size_t off = 0;
  auto take = [&](size_t sz) { size_t o = off; off = (off + sz + 255) & ~(size_t)255; return o; };
  size_t o_xbf[2]; o_xbf[0] = take(SZ_XBF); o_xbf[1] = take(SZ_XBF);
  size_t o_wtQ[2]; o_wtQ[0] = take((size_t)512 * 512 * 2); o_wtQ[1] = take((size_t)512 * 512 * 2);
  size_t o_wtC[2]; o_wtC[0] = take((size_t)512 * 1024 * 2); o_wtC[1] = take((size_t)512 * 1024 * 2);
  size_t o_wtHE = take((size_t)512 * 1024 * 2);
  size_t o_heb = take(SZ_HEB);
  size_t o_qbf = take(2 * SZ_XBF);                      // qbf_a+qbf_b; later cbf (c2 bf16 out)
  size_t o_nbf = take(2 * SZ_XBF);                      // first xaggA/B, later nbf_a, nbf_b
  size_t o_part = take((size_t)2 * NBLK_ATTN * 8 * 4);
  size_t o_stats = take(256);
  size_t o_cnt4 = take((size_t)(2 * NHE + 2 * NNODE) * 4);
  size_t o_baseH[2]; o_baseH[0] = take((NHE + 1) * 4); o_baseH[1] = take((NHE + 1) * 4);
  size_t o_baseN[2]; o_baseN[0] = take((NNODE + 1) * 4); o_baseN[1] = take((NNODE + 1) * 4);
  size_t o_nArrH[2]; o_nArrH[0] = take((size_t)NEDGE * 4); o_nArrH[1] = take((size_t)NEDGE * 4);
  size_t o_hArrN[2]; o_hArrN[0] = take((size_t)NEDGE * 4); o_hArrN[1] = take((size_t)NEDGE * 4);
  if (ws_size < off) return;

  char* ws = (char*)d_ws;
  unsigned short* xbf[2] = {(unsigned short*)(ws + o_xbf[0]), (unsigned short*)(ws + o_xbf[1])};
  unsigned short* wtQ[2] = {(unsigned short*)(ws + o_wtQ[0]), (unsigned short*)(ws + o_wtQ[1])};
  unsigned short* wtC[2] = {(unsigned short*)(ws + o_wtC[0]), (unsigned short*)(ws + o_wtC[1])};
  unsigned short* wtHE = (unsigned short*)(ws + o_wtHE);
  unsigned short* heb = (unsigned short*)(ws + o_heb);
  unsigned short* qbf[2] = {(unsigned short*)(ws + o_qbf),
                            (unsigned short*)(ws + o_qbf) + (size_t)MPAD * CCH};
  unsigned short* cbf = (unsigned short*)(ws + o_qbf);        // aliases qbf (dead after attn)
  unsigned short* xaggA = (unsigned short*)(ws + o_nbf);      // aliases nbf (dead after he GEMM)
  unsigned short* xaggB = xaggA + (size_t)NHE * CCH;
  unsigned short* nbf[2] = {(unsigned short*)(ws + o_nbf),
                            (unsigned short*)(ws + o_nbf) + (size_t)MPAD * CCH};
  float* partials = (float*)(ws + o_part);
  float* inv = (float*)(ws + o_stats);                        // 16 entries
  int* cntHA = (int*)(ws + o_cnt4);
  int* cntHB = cntHA + NHE;
  int* cntNA = cntHB + NHE;
  int* cntNB = cntNA + NNODE;
  int* baseH[2] = {(int*)(ws + o_baseH[0]), (int*)(ws + o_baseH[1])};
  int* baseN[2] = {(int*)(ws + o_baseN[0]), (int*)(ws + o_baseN[1])};
  int* nArrH[2] = {(int*)(ws + o_nArrH[0]), (int*)(ws + o_nArrH[1])};
  int* hArrN[2] = {(int*)(ws + o_hArrN[0]), (int*)(ws + o_hArrN[1])};
  float* out = (float*)d_out;

  const long nValid = (long)NNODE * CCH, nTotal = (long)MPAD * CCH;
  const int cvtHalf = (int)((nTotal / 8 + 255) / 256);   // 10016
  const int gemmBlocks = 4 * (MPAD / 128);               // 1252 per type
  const int heBlocks = 4 * (NHE / 128);                  // 512
  const int histBlocks = (NEDGE + 255) / 256;            // 469

  // 1: zero count arrays
  hipMemsetAsync(cntHA, 0, (size_t)(2 * NHE + 2 * NNODE) * 4, stream);

  // 2: x->bf16 + 6 weight transposes + 4 CSR histograms (one dispatch)
  TPack tp;
  tp.W[0] = qW[0]; tp.Wt[0] = wtQ[0]; tp.ld[0] = 512;  tp.kOff[0] = 0;
  tp.W[1] = qW[1]; tp.Wt[1] = wtQ[1]; tp.ld[1] = 512;  tp.kOff[1] = 0;
  tp.W[2] = sW[0]; tp.Wt[2] = wtC[0]; tp.ld[2] = 1024; tp.kOff[2] = 512;
  tp.W[3] = sW[1]; tp.Wt[3] = wtC[1]; tp.ld[3] = 1024; tp.kOff[3] = 512;
  tp.W[4] = kW[0]; tp.Wt[4] = wtHE;   tp.ld[4] = 1024; tp.kOff[4] = 0;
  tp.W[5] = kW[1]; tp.Wt[5] = wtHE;   tp.ld[5] = 1024; tp.kOff[5] = 512;
  prep_cvt<<<2 * cvtHalf + 6 * 1024 + histBlocks, 256, 0, stream>>>(
      x_a, x_b, xbf[0], xbf[1], nValid, nTotal, cvtHalf, tp,
      hidx[0], hidx[1], nidx[0], nidx[1], cntHA, cntHB, cntNA, cntNB, NEDGE);

  // 3-4: CSR scan + fill
  scan4<<<4, 1024, 0, stream>>>(cntHA, baseH[0], NHE, cntHB, baseH[1], NHE,
                                cntNA, baseN[0], NNODE, cntNB, baseN[1], NNODE);
  fill4<<<histBlocks, 256, 0, stream>>>(hidx[0], hidx[1], nidx[0], nidx[1],
                                        baseH[0], baseH[1], baseN[0], baseN[1],
                                        cntHA, cntHB, cntNA, cntNB,
                                        nArrH[0], nArrH[1], hArrN[0], hArrN[1], NEDGE);

  // 5: both Xagg gathers (2-deep pipelined)
  xagg2<<<2 * (NHE / 2), 256, 0, stream>>>(xbf[0], nArrH[0], baseH[0], xaggA,
                                           xbf[1], nArrH[1], baseH[1], xaggB, NHE / 2);

  // 6: he = [XaggA|XaggB] @ [kWa;kWb] + cnt*kb (bf16)
  gemm_he<<<heBlocks, 256, 0, stream>>>(xaggA, xaggB, wtHE, kb[0], kb[1],
                                        baseH[0], baseH[1], heb);

  // 7: both Q projections -> bf16
  gemm_q2<<<2 * gemmBlocks, 256, 0, stream>>>(gemmBlocks,
                                              xbf[0], wtQ[0], qb[0], qbf[0],
                                              xbf[1], wtQ[1], qb[1], qbf[1]);

  // 8: both fused attentions (overwrites xagg region with nbf)
  fused_attn2<<<2 * NBLK_ATTN, 256, 0, stream>>>(qbf[0], qbf[1], heb,
                                                 hArrN[0], baseN[0], hArrN[1], baseN[1],
                                                 nbf[0], nbf[1], partials, NBLK_ATTN);

  // 9: softmax denominators for both types
  reduce_partials2<<<16, 256, 0, stream>>>(partials, inv, NBLK_ATTN);

  // 10: fold denominators into aW halves of wtC (both types)
  tscale2<<<2 * 1024, 256, 0, stream>>>(aW[0], aW[1], inv, wtC[0], wtC[1]);

  // 11: both combined GEMMs -> bf16 scratch (cbf aliases qbf region; q dead)
  gemm_c2<<<2 * gemmBlocks, 256, 0, stream>>>(gemmBlocks,
                                              nbf[0], xbf[0], wtC[0], ab[0], sb[0], cbf,
                                              nbf[1], xbf[1], wtC[1], ab[1], sb[1],
                                              cbf + (size_t)MPAD * CCH);

  // 12: LayerNorm (bf16 in) -> final f32 out
  ln2bf<<<(2 * NNODE + 3) / 4, 256, 0, stream>>>(cbf, out, lng[0], lnb[0], lng[1], lnb[1]);
}

// Round 15
// 554.219 us; speedup vs baseline: 1.5884x; 1.5884x over previous
//
#include <hip/hip_runtime.h>
#include <cstdint>

// Problem constants (match reference setup_inputs)
#define NNODE 40000
#define NEDGE 120000
#define NHE   16384
#define CCH   512
#define MPAD  40064   // 313 * 128, padded row count for GEMM A operands

typedef __attribute__((ext_vector_type(8))) short bf16x8;
typedef __attribute__((ext_vector_type(4))) float f32x4;
typedef __attribute__((ext_vector_type(8))) unsigned short ushort8;
typedef __attribute__((ext_vector_type(4))) unsigned short ushort4v;

// ---------------------------------------------------------------- helpers
__device__ __forceinline__ unsigned short f2bf(float f) {
  unsigned int u = __float_as_uint(f);
  u += 0x7FFFu + ((u >> 16) & 1u);   // round-to-nearest-even
  return (unsigned short)(u >> 16);
}
__device__ __forceinline__ float bf2f(unsigned short u) {
  return __uint_as_float((unsigned int)u << 16);
}

__device__ __forceinline__ void g2l16(const void* g, void* l) {
  // async global->LDS, 16B per lane. LDS dest must be wave-uniform base + lane*16.
  __builtin_amdgcn_global_load_lds(
      (const __attribute__((address_space(1))) unsigned int*)(uintptr_t)g,
      (__attribute__((address_space(3))) unsigned int*)(unsigned int)(uintptr_t)l,
      16, 0, 0);
}

// bijective XCD swizzle (m204): blocks with consecutive pid land on the same XCD
__device__ __forceinline__ int xcd_pid(int lin, int nwg) {
  int xcd = lin & 7, slot = lin >> 3;
  int q = nwg >> 3, r = nwg & 7;
  return ((xcd < r) ? (xcd * (q + 1)) : (r * (q + 1) + (xcd - r) * q)) + slot;
}

// ---------------------------------------------------------------- prep: x->bf16 + 6 transposes + 4 histograms
struct TPack {
  const float* W[6];
  unsigned short* Wt[6];
  int ld[6];
  int kOff[6];
};
__global__ void prep_cvt(const float* __restrict__ xa, const float* __restrict__ xb,
                         unsigned short* __restrict__ oa, unsigned short* __restrict__ ob,
                         long nValid, long nTotal, int half, TPack p,
                         const int* __restrict__ hA, const int* __restrict__ hB,
                         const int* __restrict__ nA, const int* __restrict__ nB,
                         int* __restrict__ cntHA, int* __restrict__ cntHB,
                         int* __restrict__ cntNA, int* __restrict__ cntNB, int E) {
  int bid = blockIdx.x;
  if (bid < 2 * half) {
    int t = bid >= half;
    long i = ((long)(bid - t * half) * 256 + threadIdx.x) * 8;
    if (i >= nTotal) return;
    const float* in = t ? xb : xa;
    unsigned short* out = t ? ob : oa;
    ushort8 r;
    if (i < nValid) {
      float4 a = *(const float4*)(in + i);
      float4 b = *(const float4*)(in + i + 4);
      r[0] = f2bf(a.x); r[1] = f2bf(a.y); r[2] = f2bf(a.z); r[3] = f2bf(a.w);
      r[4] = f2bf(b.x); r[5] = f2bf(b.y); r[6] = f2bf(b.z); r[7] = f2bf(b.w);
    } else {
      for (int j = 0; j < 8; ++j) r[j] = 0;
    }
    *(ushort8*)(out + i) = r;
  } else if (bid < 2 * half + 6144) {
    int wb = bid - 2 * half;                    // 0..6143
    int which = wb >> 10;                       // 1024 blocks per matrix
    int gid = (wb & 1023) * 256 + threadIdx.x;
    int i = gid >> 9, j = gid & 511;            // W[i][j]
    p.Wt[which][(size_t)j * p.ld[which] + p.kOff[which] + i] = f2bf(p.W[which][gid]);
  } else {
    int e = (bid - 2 * half - 6144) * 256 + threadIdx.x;
    if (e >= E) return;
    atomicAdd(&cntHA[hA[e]], 1);
    atomicAdd(&cntHB[hB[e]], 1);
    atomicAdd(&cntNA[nA[e]], 1);
    atomicAdd(&cntNB[nB[e]], 1);
  }
}

// aW for both types, rows scaled by inv[t*8 + head(k)] (folds softmax denominator)
__global__ void tscale2(const float* __restrict__ Wa, const float* __restrict__ Wb,
                        const float* __restrict__ inv,
                        unsigned short* __restrict__ Wta, unsigned short* __restrict__ Wtb) {
  int t = blockIdx.x >> 10;
  int gid = (blockIdx.x & 1023) * 256 + threadIdx.x;
  int i = gid >> 9, j = gid & 511;              // W[i][j], i is the k index
  const float* W = t ? Wb : Wa;
  unsigned short* Wt = t ? Wtb : Wta;
  Wt[(size_t)j * 1024 + i] = f2bf(W[gid] * inv[t * 8 + (i >> 6)]);
}

// ---------------------------------------------------------------- CSR build
// 4 independent single-block exclusive scans; zeroes cnt in place (becomes cursor)
__global__ void scan4(int* __restrict__ c0, int* __restrict__ b0, int n0,
                      int* __restrict__ c1, int* __restrict__ b1, int n1,
                      int* __restrict__ c2, int* __restrict__ b2, int n2,
                      int* __restrict__ c3, int* __restrict__ b3, int n3) {
  __shared__ int part[1024];
  int* cnt; int* base; int n;
  if (blockIdx.x == 0) { cnt = c0; base = b0; n = n0; }
  else if (blockIdx.x == 1) { cnt = c1; base = b1; n = n1; }
  else if (blockIdx.x == 2) { cnt = c2; base = b2; n = n2; }
  else { cnt = c3; base = b3; n = n3; }
  int tid = threadIdx.x;
  int chunk = (n + 1023) >> 10;
  int lo = tid * chunk;
  int hi = lo + chunk; if (hi > n) hi = n;
  int s = 0;
  for (int i = lo; i < hi; ++i) s += cnt[i];
  part[tid] = s;
  __syncthreads();
  for (int off = 1; off < 1024; off <<= 1) {
    int v = (tid >= off) ? part[tid - off] : 0;
    __syncthreads();
    part[tid] += v;
    __syncthreads();
  }
  int excl = (tid == 0) ? 0 : part[tid - 1];
  for (int i = lo; i < hi; ++i) { base[i] = excl; excl += cnt[i]; cnt[i] = 0; }
  if (tid == 0) base[n] = part[1023];
}

// fills all 4 CSR value arrays (he-CSR stores node ids; node-CSR stores he ids)
__global__ void fill4(const int* __restrict__ hA, const int* __restrict__ hB,
                      const int* __restrict__ nA, const int* __restrict__ nB,
                      const int* __restrict__ baseHA, const int* __restrict__ baseHB,
                      const int* __restrict__ baseNA, const int* __restrict__ baseNB,
                      int* __restrict__ curHA, int* __restrict__ curHB,
                      int* __restrict__ curNA, int* __restrict__ curNB,
                      int* __restrict__ nArrHA, int* __restrict__ nArrHB,
                      int* __restrict__ hArrNA, int* __restrict__ hArrNB, int E) {
  int e = blockIdx.x * 256 + threadIdx.x;
  if (e >= E) return;
  int ha = hA[e], hb = hB[e], na = nA[e], nb = nB[e];
  int p;
  p = atomicAdd(&curHA[ha], 1); nArrHA[baseHA[ha] + p] = na;
  p = atomicAdd(&curHB[hb], 1); nArrHB[baseHB[hb] + p] = nb;
  p = atomicAdd(&curNA[na], 1); hArrNA[baseNA[na] + p] = ha;
  p = atomicAdd(&curNB[nb], 1); hArrNB[baseNB[nb] + p] = hb;
}

// ---------------------------------------------------------------- Xagg gather (both types, 2-deep pipelined)
__global__ void xagg2(const unsigned short* __restrict__ Xa, const int* __restrict__ nArrA,
                      const int* __restrict__ baseA, unsigned short* __restrict__ Oa,
                      const unsigned short* __restrict__ Xb, const int* __restrict__ nArrB,
                      const int* __restrict__ baseB, unsigned short* __restrict__ Ob, int half) {
  int t = blockIdx.x >= half;
  int bl = blockIdx.x - t * half;
  const unsigned short* X = t ? Xb : Xa;
  const int* nArr = t ? nArrB : nArrA;
  const int* base = t ? baseB : baseA;
  unsigned short* Xagg = t ? Ob : Oa;
  int h = bl * 2 + (threadIdx.x >> 7);
  if (h >= NHE) return;
  int sub = threadIdx.x & 127;
  int c4 = sub << 2;
  float ax = 0.f, ay = 0.f, az = 0.f, aw = 0.f;
  int b0 = base[h], b1 = base[h + 1];
  int n0 = (b0 < b1) ? nArr[b0] : 0;
  int n1 = (b0 + 1 < b1) ? nArr[b0 + 1] : 0;
  ushort4v vA = *(const ushort4v*)&X[(size_t)n0 * CCH + c4];
  ushort4v vB = *(const ushort4v*)&X[(size_t)n1 * CCH + c4];
  for (int i = b0; i < b1; ++i) {
    ushort4v v = vA;
    vA = vB;
    int n2 = (i + 2 < b1) ? nArr[i + 2] : 0;
    vB = *(const ushort4v*)&X[(size_t)n2 * CCH + c4];   // 2-deep prefetch
    ax += bf2f(v[0]); ay += bf2f(v[1]); az += bf2f(v[2]); aw += bf2f(v[3]);
  }
  ushort4v r = {f2bf(ax), f2bf(ay), f2bf(az), f2bf(aw)};
  *(ushort4v*)&Xagg[(size_t)h * CCH + c4] = r;
}

// ---------------------------------------------------------------- fused attention (both types, 2-deep pipelined)
__global__ void fused_attn2(const unsigned short* __restrict__ Qa,
                            const unsigned short* __restrict__ Qbb,
                            const unsigned short* __restrict__ heb,
                            const int* __restrict__ hArrA, const int* __restrict__ baseA,
                            const int* __restrict__ hArrB, const int* __restrict__ baseB,
                            unsigned short* __restrict__ nbfA, unsigned short* __restrict__ nbfB,
                            float* __restrict__ partials, int half) {
  __shared__ float lsum[8];
  if (threadIdx.x < 8) lsum[threadIdx.x] = 0.f;
  __syncthreads();
  int t = blockIdx.x >= half;
  int bl = blockIdx.x - t * half;
  const unsigned short* Qb = t ? Qbb : Qa;
  const int* hArr = t ? hArrB : hArrA;
  const int* base = t ? baseB : baseA;
  unsigned short* nbf = t ? nbfB : nbfA;
  int node = bl * 4 + (threadIdx.x >> 6);           // covers MPAD exactly
  int lane = threadIdx.x & 63;
  int d0 = lane << 3;                               // 8 channels per lane, head = lane>>3
  float acc[8] = {0.f, 0.f, 0.f, 0.f, 0.f, 0.f, 0.f, 0.f};
  float psum = 0.f;
  if (node < NNODE) {
    ushort8 qv = *(const ushort8*)&Qb[(size_t)node * CCH + d0];
    float q[8];
#pragma unroll
    for (int j = 0; j < 8; ++j) q[j] = bf2f(qv[j]);
    int i0 = base[node], i1 = base[node + 1];
    int h0 = (i0 < i1) ? hArr[i0] : 0;
    int h1 = (i0 + 1 < i1) ? hArr[i0 + 1] : 0;
    ushort8 kvA = *(const ushort8*)&heb[(size_t)h0 * CCH + d0];
    ushort8 kvB = *(const ushort8*)&heb[(size_t)h1 * CCH + d0];
    for (int i = i0; i < i1; ++i) {
      ushort8 kv = kvA;
      kvA = kvB;
      int h2 = (i + 2 < i1) ? hArr[i + 2] : 0;
      kvB = *(const ushort8*)&heb[(size_t)h2 * CCH + d0];   // 2-deep prefetch
      float k[8];
#pragma unroll
      for (int j = 0; j < 8; ++j) k[j] = bf2f(kv[j]);
      float d = q[0] * k[0] + q[1] * k[1] + q[2] * k[2] + q[3] * k[3] +
                q[4] * k[4] + q[5] * k[5] + q[6] * k[6] + q[7] * k[7];
      d += __shfl_xor(d, 1); d += __shfl_xor(d, 2); d += __shfl_xor(d, 4);
      float a = __expf(d * 0.125f);   // scale = 1/sqrt(64); logits bounded, no max pass
      psum += a;
#pragma unroll
      for (int j = 0; j < 8; ++j) acc[j] += a * k[j];
    }
  }
  ushort8 r;
#pragma unroll
  for (int j = 0; j < 8; ++j) r[j] = f2bf(acc[j]);
  *(ushort8*)&nbf[(size_t)node * CCH + d0] = r;     // pad rows get zeros
  if ((lane & 7) == 0) atomicAdd(&lsum[lane >> 3], psum);
  __syncthreads();
  if (threadIdx.x < 8) partials[(size_t)blockIdx.x * 8 + threadIdx.x] = lsum[threadIdx.x];
}

// partials[2*half][8] -> inv[16]; one block per (type,head)
__global__ void reduce_partials2(const float* __restrict__ partials, float* __restrict__ inv,
                                 int half) {
  __shared__ float ls[256];
  int hh = blockIdx.x;                    // 0..15
  int t = hh >> 3, h = hh & 7;
  float s = 0.f;
  for (int i = threadIdx.x; i < half; i += 256) s += partials[(size_t)(t * half + i) * 8 + h];
  ls[threadIdx.x] = s;
  __syncthreads();
  for (int off = 128; off > 0; off >>= 1) {
    if (threadIdx.x < off) ls[threadIdx.x] += ls[threadIdx.x + off];
    __syncthreads();
  }
  if (threadIdx.x == 0) inv[hh] = 1.0f / ls[0];
}

// ---------------------------------------------------------------- GEMM body (bf16 MFMA)
// 128x128 tile, BK=32, 2-phase double-buffered LDS (stage(next) || compute(cur)),
// one barrier per K-step. LDS = exactly 32 KB (staging 32 KB; C-tile reuses it
// at stride 128 with an XOR chunk swizzle) -> HW occupancy 5 blocks/CU via LDS.
// NOTE launch_bounds min-waves stays 4: guaranteeing 5 waves/EU capped VGPR at
// 48 and spilled acc[4][4] to scratch (round-14: WRITE 80->142MB, c2 113->330us).
// C-tile swizzle: key = ((lrow>>2)&3) ^ (lrow&3); col' = col ^ (key<<3).
// bf16 output via LDS-staged epilogue (coalesced ushort8 writes).
template <int KDIM, bool ROWCNT>
__device__ __forceinline__ void gemm_body(
    unsigned short* SH, int pid,
    const unsigned short* __restrict__ A0, const unsigned short* __restrict__ A1,
    const unsigned short* __restrict__ Bt, const float* __restrict__ bias,
    const float* __restrict__ bias2, const int* __restrict__ cntA,
    const int* __restrict__ cntB, unsigned short* __restrict__ outb, int M) {
  unsigned short* As = SH;
  unsigned short* Bs = SH + 8192;
  const int row0 = (pid >> 2) * 128;
  const int col0 = (pid & 3) * 128;
  const int tid = threadIdx.x;
  const int lane = tid & 63;
  const int w = tid >> 6;
  const int wr = w >> 1, wc = w & 1;            // 2x2 waves -> 64x64 per wave

  auto stage = [&](int buf, int kt) {
#pragma unroll
    for (int j = 0; j < 2; ++j) {
      int c = tid + j * 256;                    // 16B chunk: row = c>>2, k8 = (c&3)*8
      int r = c >> 2, k8 = (c & 3) << 3;
      const unsigned short* asrc;
      if (KDIM == 512 || kt < 512)
        asrc = A0 + (size_t)(row0 + r) * 512 + kt + k8;
      else
        asrc = A1 + (size_t)(row0 + r) * 512 + (kt - 512) + k8;
      g2l16(asrc, &As[buf * 4096 + c * 8]);
      g2l16(Bt + (size_t)(col0 + r) * KDIM + kt + k8, &Bs[buf * 4096 + c * 8]);
    }
  };

  f32x4 acc[4][4];
#pragma unroll
  for (int m = 0; m < 4; ++m)
#pragma unroll
    for (int n = 0; n < 4; ++n) acc[m][n] = f32x4{0.f, 0.f, 0.f, 0.f};

  constexpr int NSTEP = KDIM / 32;
  stage(0, 0);
  __syncthreads();                              // buf0 ready
  int buf = 0;
  const int r16 = lane & 15, kh = (lane >> 4) << 3;
  for (int s = 0; s < NSTEP; ++s) {
    if (s + 1 < NSTEP) stage(buf ^ 1, (s + 1) * 32);   // prefetch next K-tile
    bf16x8 a[4], b[4];
#pragma unroll
    for (int m = 0; m < 4; ++m)
      a[m] = *(const bf16x8*)&As[buf * 4096 + (wr * 64 + m * 16 + r16) * 32 + kh];
#pragma unroll
    for (int n = 0; n < 4; ++n)
      b[n] = *(const bf16x8*)&Bs[buf * 4096 + (wc * 64 + n * 16 + r16) * 32 + kh];
#pragma unroll
    for (int m = 0; m < 4; ++m)
#pragma unroll
      for (int n = 0; n < 4; ++n)
        acc[m][n] = __builtin_amdgcn_mfma_f32_16x16x32_bf16(a[m], b[n], acc[m][n], 0, 0, 0);
    __syncthreads();                            // drains vmcnt: next buf ready, this buf free
    buf ^= 1;
  }

  // ---- epilogue: bias (+cnt terms) -> LDS C tile (XOR chunk swizzle) -> coalesced writes
  const int c15 = lane & 15;
  const int cgrp = (lane >> 4) * 4;
  float bvv[4], bv2v[4];
#pragma unroll
  for (int n = 0; n < 4; ++n) {
    int col = col0 + wc * 64 + n * 16 + c15;
    bvv[n] = bias[col];
    if (ROWCNT) bv2v[n] = bias2[col];
    else if (bias2) bvv[n] += bias2[col];
  }
#pragma unroll
  for (int m = 0; m < 4; ++m) {
#pragma unroll
    for (int r2 = 0; r2 < 4; ++r2) {
      int lrow = wr * 64 + m * 16 + cgrp + r2;
      int key = ((lrow >> 2) & 3) ^ (lrow & 3);
      float ca = 0.f, cb = 0.f;
      if (ROWCNT) {
        int row = row0 + lrow;
        ca = (float)(cntA[row + 1] - cntA[row]);
        cb = (float)(cntB[row + 1] - cntB[row]);
      }
#pragma unroll
      for (int n = 0; n < 4; ++n) {
        float v = acc[m][n][r2];
        if (ROWCNT) v += ca * bvv[n] + cb * bv2v[n];
        else v += bvv[n];
        int colL = wc * 64 + n * 16 + c15;
        SH[lrow * 128 + (colL ^ (key << 3))] = f2bf(v);
      }
    }
  }
  __syncthreads();
#pragma unroll
  for (int j = 0; j < 8; ++j) {
    int idx = tid + j * 256;                    // 2048 ushort8 chunks
    int lrow = idx >> 4, cch = idx & 15;
    int key = ((lrow >> 2) & 3) ^ (lrow & 3);
    int grow = row0 + lrow;
    if (grow < M)
      *(ushort8*)&outb[(size_t)grow * 512 + col0 + (cch << 3)] =
          *(const ushort8*)&SH[lrow * 128 + ((cch ^ key) << 3)];
  }
}

// he GEMM: he = [XaggA|XaggB] @ [kWa;kWb] + cntA*kbA + cntB*kbB  (bf16 out)
__global__ __launch_bounds__(256, 4) void gemm_he(
    const unsigned short* __restrict__ A0, const unsigned short* __restrict__ A1,
    const unsigned short* __restrict__ Bt, const float* __restrict__ kbA,
    const float* __restrict__ kbB, const int* __restrict__ cntA,
    const int* __restrict__ cntB, unsigned short* __restrict__ outb) {
  __shared__ unsigned short SH[128 * 128];
  int pid = xcd_pid(blockIdx.x, gridDim.x);
  gemm_body<1024, true>(SH, pid, A0, A1, Bt, kbA, kbB, cntA, cntB, outb, NHE);
}

// dual Q GEMM (both types in one launch, bf16 out)
__global__ __launch_bounds__(256, 4) void gemm_q2(
    int G1,
    const unsigned short* __restrict__ Aa, const unsigned short* __restrict__ Bta,
    const float* __restrict__ biasa, unsigned short* __restrict__ outa,
    const unsigned short* __restrict__ Ab, const unsigned short* __restrict__ Btb,
    const float* __restrict__ biasb, unsigned short* __restrict__ outbB) {
  __shared__ unsigned short SH[128 * 128];
  int pid = xcd_pid(blockIdx.x, gridDim.x);
  if (pid < G1)
    gemm_body<512, false>(SH, pid, Aa, Aa, Bta, biasa, nullptr, nullptr, nullptr,
                          outa, NNODE);
  else
    gemm_body<512, false>(SH, pid - G1, Ab, Ab, Btb, biasb, nullptr, nullptr, nullptr,
                          outbB, NNODE);
}

// dual combined GEMM: cbf = bf16( nbf @ (inv*aW) + ab + x @ sW + sb )   (K=1024)
__global__ __launch_bounds__(256, 4) void gemm_c2(
    int G1,
    const unsigned short* __restrict__ A0a, const unsigned short* __restrict__ A1a,
    const unsigned short* __restrict__ Bta, const float* __restrict__ aba,
    const float* __restrict__ sba, unsigned short* __restrict__ outa,
    const unsigned short* __restrict__ A0b, const unsigned short* __restrict__ A1b,
    const unsigned short* __restrict__ Btb, const float* __restrict__ abb,
    const float* __restrict__ sbb, unsigned short* __restrict__ outb) {
  __shared__ unsigned short SH[128 * 128];
  int pid = xcd_pid(blockIdx.x, gridDim.x);
  if (pid < G1)
    gemm_body<1024, false>(SH, pid, A0a, A1a, Bta, aba, sba, nullptr, nullptr,
                           outa, NNODE);
  else
    gemm_body<1024, false>(SH, pid - G1, A0b, A1b, Btb, abb, sbb, nullptr, nullptr,
                           outb, NNODE);
}

// ---------------------------------------------------------------- LayerNorm (bf16 in, f32 out, both types)
__global__ void ln2bf(const unsigned short* __restrict__ cbf, float* __restrict__ y,
                      const float* __restrict__ ga, const float* __restrict__ ba,
                      const float* __restrict__ gb, const float* __restrict__ bb) {
  int row = blockIdx.x * 4 + (threadIdx.x >> 6);
  if (row >= 2 * NNODE) return;
  int t = row >= NNODE;
  const float* g = t ? gb : ga;
  const float* b = t ? bb : ba;
  int lane = threadIdx.x & 63;
  int d0 = lane * 8;
  const unsigned short* yr = cbf + (size_t)(t ? MPAD : 0) * CCH +
                             (size_t)(row - t * NNODE) * CCH;
  ushort8 v8 = *(const ushort8*)(yr + d0);
  float vv[8];
#pragma unroll
  for (int j = 0; j < 8; ++j) vv[j] = bf2f(v8[j]);
  float s = 0.f;
#pragma unroll
  for (int j = 0; j < 8; ++j) s += vv[j];
#pragma unroll
  for (int off = 1; off < 64; off <<= 1) s += __shfl_xor(s, off);
  float mu = s * (1.0f / 512.0f);
  float sq = 0.f;
#pragma unroll
  for (int j = 0; j < 8; ++j) { float d = vv[j] - mu; sq += d * d; }
#pragma unroll
  for (int off = 1; off < 64; off <<= 1) sq += __shfl_xor(sq, off);
  float rs = rsqrtf(sq * (1.0f / 512.0f) + 1e-5f);
  float4 g0 = *(const float4*)(g + d0), g1 = *(const float4*)(g + d0 + 4);
  float4 b0 = *(const float4*)(b + d0), b1 = *(const float4*)(b + d0 + 4);
  float gg[8] = {g0.x, g0.y, g0.z, g0.w, g1.x, g1.y, g1.z, g1.w};
  float bbv[8] = {b0.x, b0.y, b0.z, b0.w, b1.x, b1.y, b1.z, b1.w};
  float o[8];
#pragma unroll
  for (int j = 0; j < 8; ++j) o[j] = gg[j] * (vv[j] - mu) * rs + bbv[j];
  float* outr = y + (size_t)row * CCH;
  *(float4*)(outr + d0) = float4{o[0], o[1], o[2], o[3]};
  *(float4*)(outr + d0 + 4) = float4{o[4], o[5], o[6], o[7]};
}

// ---------------------------------------------------------------- host
extern "C" void kernel_launch(void* const* d_in, const int* in_sizes, int n_in,
                              void* d_out, int out_size, void* d_ws, size_t ws_size,
                              hipStream_t stream) {
  const float* x_a = (const float*)d_in[0];
  const float* x_b = (const float*)d_in[1];
  const int* nidx[2] = {(const int*)d_in[2], (const int*)d_in[4]};
  const int* hidx[2] = {(const int*)d_in[3], (const int*)d_in[5]};
  const float *kW[2], *kb[2], *qW[2], *qb[2], *aW[2], *ab[2], *sW[2], *sb[2], *lng[2], *lnb[2];
  for (int t = 0; t < 2; ++t) {
    int base = 7 + t * 10;
    kW[t] = (const float*)d_in[base + 0]; kb[t] = (const float*)d_in[base + 1];
    qW[t] = (const float*)d_in[base + 2]; qb[t] = (const float*)d_in[base + 3];
    aW[t] = (const float*)d_in[base + 4]; ab[t] = (const float*)d_in[base + 5];
    sW[t] = (const float*)d_in[base + 6]; sb[t] = (const float*)d_in[base + 7];
    lng[t] = (const float*)d_in[base + 8]; lnb[t] = (const float*)d_in[base + 9];
  }

  // ---------------- workspace layout
  const size_t SZ_XBF = (size_t)MPAD * CCH * 2;         // 41 MB
  const size_t SZ_HEB = (size_t)NHE * CCH * 2;          // 16.8 MB
  const int NBLK_ATTN = MPAD / 4;                       // 10016 per type
  size_t off = 0;
  auto take = [&](size_t sz) { size_t o = off; off = (off + sz + 255) & ~(size_t)255; return o; };
  size_t o_xbf[2]; o_xbf[0] = take(SZ_XBF); o_xbf[1] = take(SZ_XBF);
  size_t o_wtQ[2]; o_wtQ[0] = take((size_t)512 * 512 * 2); o_wtQ[1] = take((size_t)512 * 512 * 2);
  size_t o_wtC[2]; o_wtC[0] = take((size_t)512 * 1024 * 2); o_wtC[1] = take((size_t)512 * 1024 * 2);
  size_t o_wtHE = take((size_t)512 * 1024 * 2);
  size_t o_heb = take(SZ_HEB);
  size_t o_qbf = take(2 * SZ_XBF);                      // qbf_a+qbf_b; later cbf (c2 bf16 out)
  size_t o_nbf = take(2 * SZ_XBF);                      // first xaggA/B, later nbf_a, nbf_b
  size_t o_part = take((size_t)2 * NBLK_ATTN * 8 * 4);
  size_t o_stats = take(256);
  size_t o_cnt4 = take((size_t)(2 * NHE + 2 * NNODE) * 4);
  size_t o_baseH[2]; o_baseH[0] = take((NHE + 1) * 4); o_baseH[1] = take((NHE + 1) * 4);
  size_t o_baseN[2]; o_baseN[0] = take((NNODE + 1) * 4); o_baseN[1] = take((NNODE + 1) * 4);
  size_t o_nArrH[2]; o_nArrH[0] = take((size_t)NEDGE * 4); o_nArrH[1] = take((size_t)NEDGE * 4);
  size_t o_hArrN[2]; o_hArrN[0] = take((size_t)NEDGE * 4); o_hArrN[1] = take((size_t)NEDGE * 4);
  if (ws_size < off) return;

  char* ws = (char*)d_ws;
  unsigned short* xbf[2] = {(unsigned short*)(ws + o_xbf[0]), (unsigned short*)(ws + o_xbf[1])};
  unsigned short* wtQ[2] = {(unsigned short*)(ws + o_wtQ[0]), (unsigned short*)(ws + o_wtQ[1])};
  unsigned short* wtC[2] = {(unsigned short*)(ws + o_wtC[0]), (unsigned short*)(ws + o_wtC[1])};
  unsigned short* wtHE = (unsigned short*)(ws + o_wtHE);
  unsigned short* heb = (unsigned short*)(ws + o_heb);
  unsigned short* qbf[2] = {(unsigned short*)(ws + o_qbf),
                            (unsigned short*)(ws + o_qbf) + (size_t)MPAD * CCH};
  unsigned short* cbf = (unsigned short*)(ws + o_qbf);        // aliases qbf (dead after attn)
  unsigned short* xaggA = (unsigned short*)(ws + o_nbf);      // aliases nbf (dead after he GEMM)
  unsigned short* xaggB = xaggA + (size_t)NHE * CCH;
  unsigned short* nbf[2] = {(unsigned short*)(ws + o_nbf),
                            (unsigned short*)(ws + o_nbf) + (size_t)MPAD * CCH};
  float* partials = (float*)(ws + o_part);
  float* inv = (float*)(ws + o_stats);                        // 16 entries
  int* cntHA = (int*)(ws + o_cnt4);
  int* cntHB = cntHA + NHE;
  int* cntNA = cntHB + NHE;
  int* cntNB = cntNA + NNODE;
  int* baseH[2] = {(int*)(ws + o_baseH[0]), (int*)(ws + o_baseH[1])};
  int* baseN[2] = {(int*)(ws + o_baseN[0]), (int*)(ws + o_baseN[1])};
  int* nArrH[2] = {(int*)(ws + o_nArrH[0]), (int*)(ws + o_nArrH[1])};
  int* hArrN[2] = {(int*)(ws + o_hArrN[0]), (int*)(ws + o_hArrN[1])};
  float* out = (float*)d_out;

  const long nValid = (long)NNODE * CCH, nTotal = (long)MPAD * CCH;
  const int cvtHalf = (int)((nTotal / 8 + 255) / 256);   // 10016
  const int gemmBlocks = 4 * (MPAD / 128);               // 1252 per type
  const int heBlocks = 4 * (NHE / 128);                  // 512
  const int histBlocks = (NEDGE + 255) / 256;            // 469

  // 1: zero count arrays
  hipMemsetAsync(cntHA, 0, (size_t)(2 * NHE + 2 * NNODE) * 4, stream);

  // 2: x->bf16 + 6 weight transposes + 4 CSR histograms (one dispatch)
  TPack tp;
  tp.W[0] = qW[0]; tp.Wt[0] = wtQ[0]; tp.ld[0] = 512;  tp.kOff[0] = 0;
  tp.W[1] = qW[1]; tp.Wt[1] = wtQ[1]; tp.ld[1] = 512;  tp.kOff[1] = 0;
  tp.W[2] = sW[0]; tp.Wt[2] = wtC[0]; tp.ld[2] = 1024; tp.kOff[2] = 512;
  tp.W[3] = sW[1]; tp.Wt[3] = wtC[1]; tp.ld[3] = 1024; tp.kOff[3] = 512;
  tp.W[4] = kW[0]; tp.Wt[4] = wtHE;   tp.ld[4] = 1024; tp.kOff[4] = 0;
  tp.W[5] = kW[1]; tp.Wt[5] = wtHE;   tp.ld[5] = 1024; tp.kOff[5] = 512;
  prep_cvt<<<2 * cvtHalf + 6 * 1024 + histBlocks, 256, 0, stream>>>(
      x_a, x_b, xbf[0], xbf[1], nValid, nTotal, cvtHalf, tp,
      hidx[0], hidx[1], nidx[0], nidx[1], cntHA, cntHB, cntNA, cntNB, NEDGE);

  // 3-4: CSR scan + fill
  scan4<<<4, 1024, 0, stream>>>(cntHA, baseH[0], NHE, cntHB, baseH[1], NHE,
                                cntNA, baseN[0], NNODE, cntNB, baseN[1], NNODE);
  fill4<<<histBlocks, 256, 0, stream>>>(hidx[0], hidx[1], nidx[0], nidx[1],
                                        baseH[0], baseH[1], baseN[0], baseN[1],
                                        cntHA, cntHB, cntNA, cntNB,
                                        nArrH[0], nArrH[1], hArrN[0], hArrN[1], NEDGE);

  // 5: both Xagg gathers (2-deep pipelined)
  xagg2<<<2 * (NHE / 2), 256, 0, stream>>>(xbf[0], nArrH[0], baseH[0], xaggA,
                                           xbf[1], nArrH[1], baseH[1], xaggB, NHE / 2);

  // 6: he = [XaggA|XaggB] @ [kWa;kWb] + cnt*kb (bf16)
  gemm_he<<<heBlocks, 256, 0, stream>>>(xaggA, xaggB, wtHE, kb[0], kb[1],
                                        baseH[0], baseH[1], heb);

  // 7: both Q projections -> bf16
  gemm_q2<<<2 * gemmBlocks, 256, 0, stream>>>(gemmBlocks,
                                              xbf[0], wtQ[0], qb[0], qbf[0],
                                              xbf[1], wtQ[1], qb[1], qbf[1]);

  // 8: both fused attentions (overwrites xagg region with nbf)
  fused_attn2<<<2 * NBLK_ATTN, 256, 0, stream>>>(qbf[0], qbf[1], heb,
                                                 hArrN[0], baseN[0], hArrN[1], baseN[1],
                                                 nbf[0], nbf[1], partials, NBLK_ATTN);

  // 9: softmax denominators for both types
  reduce_partials2<<<16, 256, 0, stream>>>(partials, inv, NBLK_ATTN);

  // 10: fold denominators into aW halves of wtC (both types)
  tscale2<<<2 * 1024, 256, 0, stream>>>(aW[0], aW[1], inv, wtC[0], wtC[1]);

  // 11: both combined GEMMs -> bf16 scratch (cbf aliases qbf region; q dead)
  gemm_c2<<<2 * gemmBlocks, 256, 0, stream>>>(gemmBlocks,
                                              nbf[0], xbf[0], wtC[0], ab[0], sb[0], cbf,
                                              nbf[1], xbf[1], wtC[1], ab[1], sb[1],
                                              cbf + (size_t)MPAD * CCH);

  // 12: LayerNorm (bf16 in) -> final f32 out
  ln2bf<<<(2 * NNODE + 3) / 4, 256, 0, stream>>>(cbf, out, lng[0], lnb[0], lng[1], lnb[1]);
}

// Round 16
// 544.672 us; speedup vs baseline: 1.6162x; 1.0175x over previous
//
#include <hip/hip_runtime.h>
#include <cstdint>

// Problem constants (match reference setup_inputs)
#define NNODE 40000
#define NEDGE 120000
#define NHE   16384
#define CCH   512
#define MPAD  40064   // 313 * 128, padded row count for GEMM A operands

typedef __attribute__((ext_vector_type(8))) short bf16x8;
typedef __attribute__((ext_vector_type(4))) float f32x4;
typedef __attribute__((ext_vector_type(8))) unsigned short ushort8;
typedef __attribute__((ext_vector_type(4))) unsigned short ushort4v;

// ---------------------------------------------------------------- helpers
__device__ __forceinline__ unsigned short f2bf(float f) {
  unsigned int u = __float_as_uint(f);
  u += 0x7FFFu + ((u >> 16) & 1u);   // round-to-nearest-even
  return (unsigned short)(u >> 16);
}
__device__ __forceinline__ float bf2f(unsigned short u) {
  return __uint_as_float((unsigned int)u << 16);
}

__device__ __forceinline__ void g2l16(const void* g, void* l) {
  // async global->LDS, 16B per lane. LDS dest must be wave-uniform base + lane*16.
  __builtin_amdgcn_global_load_lds(
      (const __attribute__((address_space(1))) unsigned int*)(uintptr_t)g,
      (__attribute__((address_space(3))) unsigned int*)(unsigned int)(uintptr_t)l,
      16, 0, 0);
}

// bijective XCD swizzle (m204): blocks with consecutive pid land on the same XCD
__device__ __forceinline__ int xcd_pid(int lin, int nwg) {
  int xcd = lin & 7, slot = lin >> 3;
  int q = nwg >> 3, r = nwg & 7;
  return ((xcd < r) ? (xcd * (q + 1)) : (r * (q + 1) + (xcd - r) * q)) + slot;
}

// ---------------------------------------------------------------- prep: x->bf16 + 6 transposes + 4 histograms
struct TPack {
  const float* W[6];
  unsigned short* Wt[6];
  int ld[6];
  int kOff[6];
};
__global__ void prep_cvt(const float* __restrict__ xa, const float* __restrict__ xb,
                         unsigned short* __restrict__ oa, unsigned short* __restrict__ ob,
                         long nValid, long nTotal, int half, TPack p,
                         const int* __restrict__ hA, const int* __restrict__ hB,
                         const int* __restrict__ nA, const int* __restrict__ nB,
                         int* __restrict__ cntHA, int* __restrict__ cntHB,
                         int* __restrict__ cntNA, int* __restrict__ cntNB, int E) {
  int bid = blockIdx.x;
  if (bid < 2 * half) {
    int t = bid >= half;
    long i = ((long)(bid - t * half) * 256 + threadIdx.x) * 8;
    if (i >= nTotal) return;
    const float* in = t ? xb : xa;
    unsigned short* out = t ? ob : oa;
    ushort8 r;
    if (i < nValid) {
      float4 a = *(const float4*)(in + i);
      float4 b = *(const float4*)(in + i + 4);
      r[0] = f2bf(a.x); r[1] = f2bf(a.y); r[2] = f2bf(a.z); r[3] = f2bf(a.w);
      r[4] = f2bf(b.x); r[5] = f2bf(b.y); r[6] = f2bf(b.z); r[7] = f2bf(b.w);
    } else {
      for (int j = 0; j < 8; ++j) r[j] = 0;
    }
    *(ushort8*)(out + i) = r;
  } else if (bid < 2 * half + 6144) {
    int wb = bid - 2 * half;                    // 0..6143
    int which = wb >> 10;                       // 1024 blocks per matrix
    int gid = (wb & 1023) * 256 + threadIdx.x;
    int i = gid >> 9, j = gid & 511;            // W[i][j]
    p.Wt[which][(size_t)j * p.ld[which] + p.kOff[which] + i] = f2bf(p.W[which][gid]);
  } else {
    int e = (bid - 2 * half - 6144) * 256 + threadIdx.x;
    if (e >= E) return;
    atomicAdd(&cntHA[hA[e]], 1);
    atomicAdd(&cntHB[hB[e]], 1);
    atomicAdd(&cntNA[nA[e]], 1);
    atomicAdd(&cntNB[nB[e]], 1);
  }
}

// aW for both types, rows scaled by inv[t*8 + head(k)] (folds softmax denominator)
__global__ void tscale2(const float* __restrict__ Wa, const float* __restrict__ Wb,
                        const float* __restrict__ inv,
                        unsigned short* __restrict__ Wta, unsigned short* __restrict__ Wtb) {
  int t = blockIdx.x >> 10;
  int gid = (blockIdx.x & 1023) * 256 + threadIdx.x;
  int i = gid >> 9, j = gid & 511;              // W[i][j], i is the k index
  const float* W = t ? Wb : Wa;
  unsigned short* Wt = t ? Wtb : Wta;
  Wt[(size_t)j * 1024 + i] = f2bf(W[gid] * inv[t * 8 + (i >> 6)]);
}

// ---------------------------------------------------------------- CSR build
// 4 independent single-block exclusive scans; zeroes cnt in place (becomes cursor)
__global__ void scan4(int* __restrict__ c0, int* __restrict__ b0, int n0,
                      int* __restrict__ c1, int* __restrict__ b1, int n1,
                      int* __restrict__ c2, int* __restrict__ b2, int n2,
                      int* __restrict__ c3, int* __restrict__ b3, int n3) {
  __shared__ int part[1024];
  int* cnt; int* base; int n;
  if (blockIdx.x == 0) { cnt = c0; base = b0; n = n0; }
  else if (blockIdx.x == 1) { cnt = c1; base = b1; n = n1; }
  else if (blockIdx.x == 2) { cnt = c2; base = b2; n = n2; }
  else { cnt = c3; base = b3; n = n3; }
  int tid = threadIdx.x;
  int chunk = (n + 1023) >> 10;
  int lo = tid * chunk;
  int hi = lo + chunk; if (hi > n) hi = n;
  int s = 0;
  for (int i = lo; i < hi; ++i) s += cnt[i];
  part[tid] = s;
  __syncthreads();
  for (int off = 1; off < 1024; off <<= 1) {
    int v = (tid >= off) ? part[tid - off] : 0;
    __syncthreads();
    part[tid] += v;
    __syncthreads();
  }
  int excl = (tid == 0) ? 0 : part[tid - 1];
  for (int i = lo; i < hi; ++i) { base[i] = excl; excl += cnt[i]; cnt[i] = 0; }
  if (tid == 0) base[n] = part[1023];
}

// fills all 4 CSR value arrays (he-CSR stores node ids; node-CSR stores he ids)
__global__ void fill4(const int* __restrict__ hA, const int* __restrict__ hB,
                      const int* __restrict__ nA, const int* __restrict__ nB,
                      const int* __restrict__ baseHA, const int* __restrict__ baseHB,
                      const int* __restrict__ baseNA, const int* __restrict__ baseNB,
                      int* __restrict__ curHA, int* __restrict__ curHB,
                      int* __restrict__ curNA, int* __restrict__ curNB,
                      int* __restrict__ nArrHA, int* __restrict__ nArrHB,
                      int* __restrict__ hArrNA, int* __restrict__ hArrNB, int E) {
  int e = blockIdx.x * 256 + threadIdx.x;
  if (e >= E) return;
  int ha = hA[e], hb = hB[e], na = nA[e], nb = nB[e];
  int p;
  p = atomicAdd(&curHA[ha], 1); nArrHA[baseHA[ha] + p] = na;
  p = atomicAdd(&curHB[hb], 1); nArrHB[baseHB[hb] + p] = nb;
  p = atomicAdd(&curNA[na], 1); hArrNA[baseNA[na] + p] = ha;
  p = atomicAdd(&curNB[nb], 1); hArrNB[baseNB[nb] + p] = hb;
}

// ---------------------------------------------------------------- Xagg gather
// 16B/lane (coalescing sweet spot, G13): 64 threads per he-row, 4 rows/block,
// 2-deep prefetch. Halves VMEM instruction count vs the 8B/lane version.
__global__ void xagg2(const unsigned short* __restrict__ Xa, const int* __restrict__ nArrA,
                      const int* __restrict__ baseA, unsigned short* __restrict__ Oa,
                      const unsigned short* __restrict__ Xb, const int* __restrict__ nArrB,
                      const int* __restrict__ baseB, unsigned short* __restrict__ Ob, int half) {
  int t = blockIdx.x >= half;
  int bl = blockIdx.x - t * half;
  const unsigned short* X = t ? Xb : Xa;
  const int* nArr = t ? nArrB : nArrA;
  const int* base = t ? baseB : baseA;
  unsigned short* Xagg = t ? Ob : Oa;
  int h = bl * 4 + (threadIdx.x >> 6);
  if (h >= NHE) return;
  int sub = threadIdx.x & 63;
  int c8 = sub << 3;
  float acc[8] = {0.f, 0.f, 0.f, 0.f, 0.f, 0.f, 0.f, 0.f};
  int b0 = base[h], b1 = base[h + 1];
  int n0 = (b0 < b1) ? nArr[b0] : 0;
  int n1 = (b0 + 1 < b1) ? nArr[b0 + 1] : 0;
  ushort8 vA = *(const ushort8*)&X[(size_t)n0 * CCH + c8];
  ushort8 vB = *(const ushort8*)&X[(size_t)n1 * CCH + c8];
  for (int i = b0; i < b1; ++i) {
    ushort8 v = vA;
    vA = vB;
    int n2 = (i + 2 < b1) ? nArr[i + 2] : 0;
    vB = *(const ushort8*)&X[(size_t)n2 * CCH + c8];   // 2-deep prefetch
#pragma unroll
    for (int j = 0; j < 8; ++j) acc[j] += bf2f(v[j]);
  }
  ushort8 r;
#pragma unroll
  for (int j = 0; j < 8; ++j) r[j] = f2bf(acc[j]);
  *(ushort8*)&Xagg[(size_t)h * CCH + c8] = r;
}

// ---------------------------------------------------------------- fused attention (both types, 2-deep pipelined)
__global__ void fused_attn2(const unsigned short* __restrict__ Qa,
                            const unsigned short* __restrict__ Qbb,
                            const unsigned short* __restrict__ heb,
                            const int* __restrict__ hArrA, const int* __restrict__ baseA,
                            const int* __restrict__ hArrB, const int* __restrict__ baseB,
                            unsigned short* __restrict__ nbfA, unsigned short* __restrict__ nbfB,
                            float* __restrict__ partials, int half) {
  __shared__ float lsum[8];
  if (threadIdx.x < 8) lsum[threadIdx.x] = 0.f;
  __syncthreads();
  int t = blockIdx.x >= half;
  int bl = blockIdx.x - t * half;
  const unsigned short* Qb = t ? Qbb : Qa;
  const int* hArr = t ? hArrB : hArrA;
  const int* base = t ? baseB : baseA;
  unsigned short* nbf = t ? nbfB : nbfA;
  int node = bl * 4 + (threadIdx.x >> 6);           // covers MPAD exactly
  int lane = threadIdx.x & 63;
  int d0 = lane << 3;                               // 8 channels per lane, head = lane>>3
  float acc[8] = {0.f, 0.f, 0.f, 0.f, 0.f, 0.f, 0.f, 0.f};
  float psum = 0.f;
  if (node < NNODE) {
    ushort8 qv = *(const ushort8*)&Qb[(size_t)node * CCH + d0];
    float q[8];
#pragma unroll
    for (int j = 0; j < 8; ++j) q[j] = bf2f(qv[j]);
    int i0 = base[node], i1 = base[node + 1];
    int h0 = (i0 < i1) ? hArr[i0] : 0;
    int h1 = (i0 + 1 < i1) ? hArr[i0 + 1] : 0;
    ushort8 kvA = *(const ushort8*)&heb[(size_t)h0 * CCH + d0];
    ushort8 kvB = *(const ushort8*)&heb[(size_t)h1 * CCH + d0];
    for (int i = i0; i < i1; ++i) {
      ushort8 kv = kvA;
      kvA = kvB;
      int h2 = (i + 2 < i1) ? hArr[i + 2] : 0;
      kvB = *(const ushort8*)&heb[(size_t)h2 * CCH + d0];   // 2-deep prefetch
      float k[8];
#pragma unroll
      for (int j = 0; j < 8; ++j) k[j] = bf2f(kv[j]);
      float d = q[0] * k[0] + q[1] * k[1] + q[2] * k[2] + q[3] * k[3] +
                q[4] * k[4] + q[5] * k[5] + q[6] * k[6] + q[7] * k[7];
      d += __shfl_xor(d, 1); d += __shfl_xor(d, 2); d += __shfl_xor(d, 4);
      float a = __expf(d * 0.125f);   // scale = 1/sqrt(64); logits bounded, no max pass
      psum += a;
#pragma unroll
      for (int j = 0; j < 8; ++j) acc[j] += a * k[j];
    }
  }
  ushort8 r;
#pragma unroll
  for (int j = 0; j < 8; ++j) r[j] = f2bf(acc[j]);
  *(ushort8*)&nbf[(size_t)node * CCH + d0] = r;     // pad rows get zeros
  if ((lane & 7) == 0) atomicAdd(&lsum[lane >> 3], psum);
  __syncthreads();
  if (threadIdx.x < 8) partials[(size_t)blockIdx.x * 8 + threadIdx.x] = lsum[threadIdx.x];
}

// partials[2*half][8] -> inv[16]; one block per (type,head)
__global__ void reduce_partials2(const float* __restrict__ partials, float* __restrict__ inv,
                                 int half) {
  __shared__ float ls[256];
  int hh = blockIdx.x;                    // 0..15
  int t = hh >> 3, h = hh & 7;
  float s = 0.f;
  for (int i = threadIdx.x; i < half; i += 256) s += partials[(size_t)(t * half + i) * 8 + h];
  ls[threadIdx.x] = s;
  __syncthreads();
  for (int off = 128; off > 0; off >>= 1) {
    if (threadIdx.x < off) ls[threadIdx.x] += ls[threadIdx.x + off];
    __syncthreads();
  }
  if (threadIdx.x == 0) inv[hh] = 1.0f / ls[0];
}

// ---------------------------------------------------------------- GEMM body (bf16 MFMA)
// 128x128 tile, BK=32, 2-phase double-buffered LDS (stage(next) || compute(cur)),
// one barrier per K-step. LDS = exactly 32 KB (staging 32 KB; C-tile reuses it
// at stride 128 with an XOR chunk swizzle). launch_bounds min-waves = 4:
// forcing 5 capped VGPR at 48 and spilled acc to scratch (round-14 regression).
// C-tile swizzle: key = ((lrow>>2)&3) ^ (lrow&3); col' = col ^ (key<<3).
// bf16 output via LDS-staged epilogue (coalesced ushort8 writes).
template <int KDIM, bool ROWCNT>
__device__ __forceinline__ void gemm_body(
    unsigned short* SH, int pid,
    const unsigned short* __restrict__ A0, const unsigned short* __restrict__ A1,
    const unsigned short* __restrict__ Bt, const float* __restrict__ bias,
    const float* __restrict__ bias2, const int* __restrict__ cntA,
    const int* __restrict__ cntB, unsigned short* __restrict__ outb, int M) {
  unsigned short* As = SH;
  unsigned short* Bs = SH + 8192;
  const int row0 = (pid >> 2) * 128;
  const int col0 = (pid & 3) * 128;
  const int tid = threadIdx.x;
  const int lane = tid & 63;
  const int w = tid >> 6;
  const int wr = w >> 1, wc = w & 1;            // 2x2 waves -> 64x64 per wave

  auto stage = [&](int buf, int kt) {
#pragma unroll
    for (int j = 0; j < 2; ++j) {
      int c = tid + j * 256;                    // 16B chunk: row = c>>2, k8 = (c&3)*8
      int r = c >> 2, k8 = (c & 3) << 3;
      const unsigned short* asrc;
      if (KDIM == 512 || kt < 512)
        asrc = A0 + (size_t)(row0 + r) * 512 + kt + k8;
      else
        asrc = A1 + (size_t)(row0 + r) * 512 + (kt - 512) + k8;
      g2l16(asrc, &As[buf * 4096 + c * 8]);
      g2l16(Bt + (size_t)(col0 + r) * KDIM + kt + k8, &Bs[buf * 4096 + c * 8]);
    }
  };

  f32x4 acc[4][4];
#pragma unroll
  for (int m = 0; m < 4; ++m)
#pragma unroll
    for (int n = 0; n < 4; ++n) acc[m][n] = f32x4{0.f, 0.f, 0.f, 0.f};

  constexpr int NSTEP = KDIM / 32;
  stage(0, 0);
  __syncthreads();                              // buf0 ready
  int buf = 0;
  const int r16 = lane & 15, kh = (lane >> 4) << 3;
  for (int s = 0; s < NSTEP; ++s) {
    if (s + 1 < NSTEP) stage(buf ^ 1, (s + 1) * 32);   // prefetch next K-tile
    bf16x8 a[4], b[4];
#pragma unroll
    for (int m = 0; m < 4; ++m)
      a[m] = *(const bf16x8*)&As[buf * 4096 + (wr * 64 + m * 16 + r16) * 32 + kh];
#pragma unroll
    for (int n = 0; n < 4; ++n)
      b[n] = *(const bf16x8*)&Bs[buf * 4096 + (wc * 64 + n * 16 + r16) * 32 + kh];
#pragma unroll
    for (int m = 0; m < 4; ++m)
#pragma unroll
      for (int n = 0; n < 4; ++n)
        acc[m][n] = __builtin_amdgcn_mfma_f32_16x16x32_bf16(a[m], b[n], acc[m][n], 0, 0, 0);
    __syncthreads();                            // drains vmcnt: next buf ready, this buf free
    buf ^= 1;
  }

  // ---- epilogue: bias (+cnt terms) -> LDS C tile (XOR chunk swizzle) -> coalesced writes
  const int c15 = lane & 15;
  const int cgrp = (lane >> 4) * 4;
  float bvv[4], bv2v[4];
#pragma unroll
  for (int n = 0; n < 4; ++n) {
    int col = col0 + wc * 64 + n * 16 + c15;
    bvv[n] = bias[col];
    if (ROWCNT) bv2v[n] = bias2[col];
    else if (bias2) bvv[n] += bias2[col];
  }
#pragma unroll
  for (int m = 0; m < 4; ++m) {
#pragma unroll
    for (int r2 = 0; r2 < 4; ++r2) {
      int lrow = wr * 64 + m * 16 + cgrp + r2;
      int key = ((lrow >> 2) & 3) ^ (lrow & 3);
      float ca = 0.f, cb = 0.f;
      if (ROWCNT) {
        int row = row0 + lrow;
        ca = (float)(cntA[row + 1] - cntA[row]);
        cb = (float)(cntB[row + 1] - cntB[row]);
      }
#pragma unroll
      for (int n = 0; n < 4; ++n) {
        float v = acc[m][n][r2];
        if (ROWCNT) v += ca * bvv[n] + cb * bv2v[n];
        else v += bvv[n];
        int colL = wc * 64 + n * 16 + c15;
        SH[lrow * 128 + (colL ^ (key << 3))] = f2bf(v);
      }
    }
  }
  __syncthreads();
#pragma unroll
  for (int j = 0; j < 8; ++j) {
    int idx = tid + j * 256;                    // 2048 ushort8 chunks
    int lrow = idx >> 4, cch = idx & 15;
    int key = ((lrow >> 2) & 3) ^ (lrow & 3);
    int grow = row0 + lrow;
    if (grow < M)
      *(ushort8*)&outb[(size_t)grow * 512 + col0 + (cch << 3)] =
          *(const ushort8*)&SH[lrow * 128 + ((cch ^ key) << 3)];
  }
}

// he GEMM: he = [XaggA|XaggB] @ [kWa;kWb] + cntA*kbA + cntB*kbB  (bf16 out)
__global__ __launch_bounds__(256, 4) void gemm_he(
    const unsigned short* __restrict__ A0, const unsigned short* __restrict__ A1,
    const unsigned short* __restrict__ Bt, const float* __restrict__ kbA,
    const float* __restrict__ kbB, const int* __restrict__ cntA,
    const int* __restrict__ cntB, unsigned short* __restrict__ outb) {
  __shared__ unsigned short SH[128 * 128];
  int pid = xcd_pid(blockIdx.x, gridDim.x);
  gemm_body<1024, true>(SH, pid, A0, A1, Bt, kbA, kbB, cntA, cntB, outb, NHE);
}

// dual Q GEMM (both types in one launch, bf16 out)
__global__ __launch_bounds__(256, 4) void gemm_q2(
    int G1,
    const unsigned short* __restrict__ Aa, const unsigned short* __restrict__ Bta,
    const float* __restrict__ biasa, unsigned short* __restrict__ outa,
    const unsigned short* __restrict__ Ab, const unsigned short* __restrict__ Btb,
    const float* __restrict__ biasb, unsigned short* __restrict__ outbB) {
  __shared__ unsigned short SH[128 * 128];
  int pid = xcd_pid(blockIdx.x, gridDim.x);
  if (pid < G1)
    gemm_body<512, false>(SH, pid, Aa, Aa, Bta, biasa, nullptr, nullptr, nullptr,
                          outa, NNODE);
  else
    gemm_body<512, false>(SH, pid - G1, Ab, Ab, Btb, biasb, nullptr, nullptr, nullptr,
                          outbB, NNODE);
}

// dual combined GEMM: cbf = bf16( nbf @ (inv*aW) + ab + x @ sW + sb )   (K=1024)
__global__ __launch_bounds__(256, 4) void gemm_c2(
    int G1,
    const unsigned short* __restrict__ A0a, const unsigned short* __restrict__ A1a,
    const unsigned short* __restrict__ Bta, const float* __restrict__ aba,
    const float* __restrict__ sba, unsigned short* __restrict__ outa,
    const unsigned short* __restrict__ A0b, const unsigned short* __restrict__ A1b,
    const unsigned short* __restrict__ Btb, const float* __restrict__ abb,
    const float* __restrict__ sbb, unsigned short* __restrict__ outb) {
  __shared__ unsigned short SH[128 * 128];
  int pid = xcd_pid(blockIdx.x, gridDim.x);
  if (pid < G1)
    gemm_body<1024, false>(SH, pid, A0a, A1a, Bta, aba, sba, nullptr, nullptr,
                           outa, NNODE);
  else
    gemm_body<1024, false>(SH, pid - G1, A0b, A1b, Btb, abb, sbb, nullptr, nullptr,
                           outb, NNODE);
}

// ---------------------------------------------------------------- LayerNorm (bf16 in, f32 out, both types)
__global__ void ln2bf(const unsigned short* __restrict__ cbf, float* __restrict__ y,
                      const float* __restrict__ ga, const float* __restrict__ ba,
                      const float* __restrict__ gb, const float* __restrict__ bb) {
  int row = blockIdx.x * 4 + (threadIdx.x >> 6);
  if (row >= 2 * NNODE) return;
  int t = row >= NNODE;
  const float* g = t ? gb : ga;
  const float* b = t ? bb : ba;
  int lane = threadIdx.x & 63;
  int d0 = lane * 8;
  const unsigned short* yr = cbf + (size_t)(t ? MPAD : 0) * CCH +
                             (size_t)(row - t * NNODE) * CCH;
  ushort8 v8 = *(const ushort8*)(yr + d0);
  float vv[8];
#pragma unroll
  for (int j = 0; j < 8; ++j) vv[j] = bf2f(v8[j]);
  float s = 0.f;
#pragma unroll
  for (int j = 0; j < 8; ++j) s += vv[j];
#pragma unroll
  for (int off = 1; off < 64; off <<= 1) s += __shfl_xor(s, off);
  float mu = s * (1.0f / 512.0f);
  float sq = 0.f;
#pragma unroll
  for (int j = 0; j < 8; ++j) { float d = vv[j] - mu; sq += d * d; }
#pragma unroll
  for (int off = 1; off < 64; off <<= 1) sq += __shfl_xor(sq, off);
  float rs = rsqrtf(sq * (1.0f / 512.0f) + 1e-5f);
  float4 g0 = *(const float4*)(g + d0), g1 = *(const float4*)(g + d0 + 4);
  float4 b0 = *(const float4*)(b + d0), b1 = *(const float4*)(b + d0 + 4);
  float gg[8] = {g0.x, g0.y, g0.z, g0.w, g1.x, g1.y, g1.z, g1.w};
  float bbv[8] = {b0.x, b0.y, b0.z, b0.w, b1.x, b1.y, b1.z, b1.w};
  float o[8];
#pragma unroll
  for (int j = 0; j < 8; ++j) o[j] = gg[j] * (vv[j] - mu) * rs + bbv[j];
  float* outr = y + (size_t)row * CCH;
  *(float4*)(outr + d0) = float4{o[0], o[1], o[2], o[3]};
  *(float4*)(outr + d0 + 4) = float4{o[4], o[5], o[6], o[7]};
}

// ---------------------------------------------------------------- host
extern "C" void kernel_launch(void* const* d_in, const int* in_sizes, int n_in,
                              void* d_out, int out_size, void* d_ws, size_t ws_size,
                              hipStream_t stream) {
  const float* x_a = (const float*)d_in[0];
  const float* x_b = (const float*)d_in[1];
  const int* nidx[2] = {(const int*)d_in[2], (const int*)d_in[4]};
  const int* hidx[2] = {(const int*)d_in[3], (const int*)d_in[5]};
  const float *kW[2], *kb[2], *qW[2], *qb[2], *aW[2], *ab[2], *sW[2], *sb[2], *lng[2], *lnb[2];
  for (int t = 0; t < 2; ++t) {
    int base = 7 + t * 10;
    kW[t] = (const float*)d_in[base + 0]; kb[t] = (const float*)d_in[base + 1];
    qW[t] = (const float*)d_in[base + 2]; qb[t] = (const float*)d_in[base + 3];
    aW[t] = (const float*)d_in[base + 4]; ab[t] = (const float*)d_in[base + 5];
    sW[t] = (const float*)d_in[base + 6]; sb[t] = (const float*)d_in[base + 7];
    lng[t] = (const float*)d_in[base + 8]; lnb[t] = (const float*)d_in[base + 9];
  }

  // ---------------- workspace layout
  const size_t SZ_XBF = (size_t)MPAD * CCH * 2;         // 41 MB
  const size_t SZ_HEB = (size_t)NHE * CCH * 2;          // 16.8 MB
  const int NBLK_ATTN = MPAD / 4;                       // 10016 per type
  size_t off = 0;
  auto take = [&](size_t sz) { size_t o = off; off = (off + sz + 255) & ~(size_t)255; return o; };
  size_t o_xbf[2]; o_xbf[0] = take(SZ_XBF); o_xbf[1] = take(SZ_XBF);
  size_t o_wtQ[2]; o_wtQ[0] = take((size_t)512 * 512 * 2); o_wtQ[1] = take((size_t)512 * 512 * 2);
  size_t o_wtC[2]; o_wtC[0] = take((size_t)512 * 1024 * 2); o_wtC[1] = take((size_t)512 * 1024 * 2);
  size_t o_wtHE = take((size_t)512 * 1024 * 2);
  size_t o_heb = take(SZ_HEB);
  size_t o_qbf = take(2 * SZ_XBF);                      // qbf_a+qbf_b; later cbf (c2 bf16 out)
  size_t o_nbf = take(2 * SZ_XBF);                      // first xaggA/B, later nbf_a, nbf_b
  size_t o_part = take((size_t)2 * NBLK_ATTN * 8 * 4);
  size_t o_stats = take(256);
  size_t o_cnt4 = take((size_t)(2 * NHE + 2 * NNODE) * 4);
  size_t o_baseH[2]; o_baseH[0] = take((NHE + 1) * 4); o_baseH[1] = take((NHE + 1) * 4);
  size_t o_baseN[2]; o_baseN[0] = take((NNODE + 1) * 4); o_baseN[1] = take((NNODE + 1) * 4);
  size_t o_nArrH[2]; o_nArrH[0] = take((size_t)NEDGE * 4); o_nArrH[1] = take((size_t)NEDGE * 4);
  size_t o_hArrN[2]; o_hArrN[0] = take((size_t)NEDGE * 4); o_hArrN[1] = take((size_t)NEDGE * 4);
  if (ws_size < off) return;

  char* ws = (char*)d_ws;
  unsigned short* xbf[2] = {(unsigned short*)(ws + o_xbf[0]), (unsigned short*)(ws + o_xbf[1])};
  unsigned short* wtQ[2] = {(unsigned short*)(ws + o_wtQ[0]), (unsigned short*)(ws + o_wtQ[1])};
  unsigned short* wtC[2] = {(unsigned short*)(ws + o_wtC[0]), (unsigned short*)(ws + o_wtC[1])};
  unsigned short* wtHE = (unsigned short*)(ws + o_wtHE);
  unsigned short* heb = (unsigned short*)(ws + o_heb);
  unsigned short* qbf[2] = {(unsigned short*)(ws + o_qbf),
                            (unsigned short*)(ws + o_qbf) + (size_t)MPAD * CCH};
  unsigned short* cbf = (unsigned short*)(ws + o_qbf);        // aliases qbf (dead after attn)
  unsigned short* xaggA = (unsigned short*)(ws + o_nbf);      // aliases nbf (dead after he GEMM)
  unsigned short* xaggB = xaggA + (size_t)NHE * CCH;
  unsigned short* nbf[2] = {(unsigned short*)(ws + o_nbf),
                            (unsigned short*)(ws + o_nbf) + (size_t)MPAD * CCH};
  float* partials = (float*)(ws + o_part);
  float* inv = (float*)(ws + o_stats);                        // 16 entries
  int* cntHA = (int*)(ws + o_cnt4);
  int* cntHB = cntHA + NHE;
  int* cntNA = cntHB + NHE;
  int* cntNB = cntNA + NNODE;
  int* baseH[2] = {(int*)(ws + o_baseH[0]), (int*)(ws + o_baseH[1])};
  int* baseN[2] = {(int*)(ws + o_baseN[0]), (int*)(ws + o_baseN[1])};
  int* nArrH[2] = {(int*)(ws + o_nArrH[0]), (int*)(ws + o_nArrH[1])};
  int* hArrN[2] = {(int*)(ws + o_hArrN[0]), (int*)(ws + o_hArrN[1])};
  float* out = (float*)d_out;

  const long nValid = (long)NNODE * CCH, nTotal = (long)MPAD * CCH;
  const int cvtHalf = (int)((nTotal / 8 + 255) / 256);   // 10016
  const int gemmBlocks = 4 * (MPAD / 128);               // 1252 per type
  const int heBlocks = 4 * (NHE / 128);                  // 512
  const int histBlocks = (NEDGE + 255) / 256;            // 469

  // 1: zero count arrays
  hipMemsetAsync(cntHA, 0, (size_t)(2 * NHE + 2 * NNODE) * 4, stream);

  // 2: x->bf16 + 6 weight transposes + 4 CSR histograms (one dispatch)
  TPack tp;
  tp.W[0] = qW[0]; tp.Wt[0] = wtQ[0]; tp.ld[0] = 512;  tp.kOff[0] = 0;
  tp.W[1] = qW[1]; tp.Wt[1] = wtQ[1]; tp.ld[1] = 512;  tp.kOff[1] = 0;
  tp.W[2] = sW[0]; tp.Wt[2] = wtC[0]; tp.ld[2] = 1024; tp.kOff[2] = 512;
  tp.W[3] = sW[1]; tp.Wt[3] = wtC[1]; tp.ld[3] = 1024; tp.kOff[3] = 512;
  tp.W[4] = kW[0]; tp.Wt[4] = wtHE;   tp.ld[4] = 1024; tp.kOff[4] = 0;
  tp.W[5] = kW[1]; tp.Wt[5] = wtHE;   tp.ld[5] = 1024; tp.kOff[5] = 512;
  prep_cvt<<<2 * cvtHalf + 6 * 1024 + histBlocks, 256, 0, stream>>>(
      x_a, x_b, xbf[0], xbf[1], nValid, nTotal, cvtHalf, tp,
      hidx[0], hidx[1], nidx[0], nidx[1], cntHA, cntHB, cntNA, cntNB, NEDGE);

  // 3-4: CSR scan + fill
  scan4<<<4, 1024, 0, stream>>>(cntHA, baseH[0], NHE, cntHB, baseH[1], NHE,
                                cntNA, baseN[0], NNODE, cntNB, baseN[1], NNODE);
  fill4<<<histBlocks, 256, 0, stream>>>(hidx[0], hidx[1], nidx[0], nidx[1],
                                        baseH[0], baseH[1], baseN[0], baseN[1],
                                        cntHA, cntHB, cntNA, cntNB,
                                        nArrH[0], nArrH[1], hArrN[0], hArrN[1], NEDGE);

  // 5: both Xagg gathers (16B/lane, 2-deep pipelined)
  xagg2<<<2 * (NHE / 4), 256, 0, stream>>>(xbf[0], nArrH[0], baseH[0], xaggA,
                                           xbf[1], nArrH[1], baseH[1], xaggB, NHE / 4);

  // 6: he = [XaggA|XaggB] @ [kWa;kWb] + cnt*kb (bf16)
  gemm_he<<<heBlocks, 256, 0, stream>>>(xaggA, xaggB, wtHE, kb[0], kb[1],
                                        baseH[0], baseH[1], heb);

  // 7: both Q projections -> bf16
  gemm_q2<<<2 * gemmBlocks, 256, 0, stream>>>(gemmBlocks,
                                              xbf[0], wtQ[0], qb[0], qbf[0],
                                              xbf[1], wtQ[1], qb[1], qbf[1]);

  // 8: both fused attentions (overwrites xagg region with nbf)
  fused_attn2<<<2 * NBLK_ATTN, 256, 0, stream>>>(qbf[0], qbf[1], heb,
                                                 hArrN[0], baseN[0], hArrN[1], baseN[1],
                                                 nbf[0], nbf[1], partials, NBLK_ATTN);

  // 9: softmax denominators for both types
  reduce_partials2<<<16, 256, 0, stream>>>(partials, inv, NBLK_ATTN);

  // 10: fold denominators into aW halves of wtC (both types)
  tscale2<<<2 * 1024, 256, 0, stream>>>(aW[0], aW[1], inv, wtC[0], wtC[1]);

  // 11: both combined GEMMs -> bf16 scratch (cbf aliases qbf region; q dead)
  gemm_c2<<<2 * gemmBlocks, 256, 0, stream>>>(gemmBlocks,
                                              nbf[0], xbf[0], wtC[0], ab[0], sb[0], cbf,
                                              nbf[1], xbf[1], wtC[1], ab[1], sb[1],
                                              cbf + (size_t)MPAD * CCH);

  // 12: LayerNorm (bf16 in) -> final f32 out
  ln2bf<<<(2 * NNODE + 3) / 4, 256, 0, stream>>>(cbf, out, lng[0], lnb[0], lng[1], lnb[1]);
}